// Round 12
// baseline (747.635 us; speedup 1.0000x reference)
//
#include <hip/hip_runtime.h>
#include <math.h>
#include <stdint.h>

// ---------------------------------------------------------------------------
// GroundingModule — round 12: B-operands direct from L2 to registers (B panels
// are L2-resident and block-shared); LDS holds A only (2 x 16KB dbuf).
// Single-phase k-loop: {ds_read A || stage A(kt+1) || load B(kt+1)} ->
// VMW(12) -> lgkm -> 48 MFMA -> VMW(8) -> ONE barrier.  (round 11: 6 barriers,
// 192KB LDS traffic per k-tile; now 1 barrier, 96KB.)
// Core otherwise unchanged: 2 blocks/CU, 256 thr / 4 waves (2x2), 128x128
// tile, split-bf16 3-term, slot-XOR swizzle on A, cheap gelu epilogue.
// ---------------------------------------------------------------------------

#define DEV __device__ __forceinline__

typedef __attribute__((ext_vector_type(8))) short short8v;   // 8 bf16
typedef __attribute__((ext_vector_type(4))) float f32x4;

constexpr int KDIM  = 768;
constexpr int CHUNK = 32768;

// output offsets (floats) in return order
constexpr int OFF_KG   = 0;
constexpr int OFF_MI   = 65536;
constexpr int OFF_ST   = 69632;
constexpr int OFF_ET   = 71680;
constexpr int OFF_MASK = 73728;
constexpr int OFF_ORI  = 139264;

DEV float wave_sum(float v) { for (int o = 32; o; o >>= 1) v += __shfl_xor(v, o); return v; }
DEV float wave_max(float v) { for (int o = 32; o; o >>= 1) v = fmaxf(v, __shfl_xor(v, o)); return v; }

// branchless gelu: 0.5x(1+erf(x/sqrt2)), erf via A&S 7.1.26 (|err|<=1.5e-7)
DEV float gelu_fast(float x) {
    float z = x * 0.70710678118654752f;
    float s = fabsf(z);
    float t = __builtin_amdgcn_rcpf(fmaf(0.3275911f, s, 1.0f));
    float p = t * fmaf(t, fmaf(t, fmaf(t, fmaf(t, 1.061405429f, -1.453152027f),
                                       1.421413741f), -0.284496736f), 0.254829592f);
    float e = __expf(-s * s);
    float er = copysignf(1.0f - p * e, z);
    return 0.5f * x * (1.0f + er);
}

DEV short f2bf(float x) {                       // f32 -> bf16 (RNE)
    uint32_t u = __builtin_bit_cast(uint32_t, x);
    u = u + 0x7fffu + ((u >> 16) & 1u);
    return (short)(u >> 16);
}
DEV float bf2f(short b) {
    uint32_t u = ((uint32_t)(uint16_t)b) << 16;
    return __builtin_bit_cast(float, u);
}
DEV float asf(uint32_t u) { return __builtin_bit_cast(float, u); }

DEV void gl_lds16(const void* g, void* l) {     // async 16B/lane global->LDS
    __builtin_amdgcn_global_load_lds(
        (const __attribute__((address_space(1))) uint32_t*)g,
        (__attribute__((address_space(3))) uint32_t*)l, 16, 0, 0);
}

// ---------------------------------------------------------------------------
// prep_A1: fused rowstats + LN-affine + hi/lo split.  One wave per row.
__global__ __launch_bounds__(256)
void prep_A1(const float* __restrict__ X, const float* __restrict__ g,
             const float* __restrict__ b, short* __restrict__ Ah, short* __restrict__ Al)
{
    int w = threadIdx.x >> 6, lane = threadIdx.x & 63;
    int row = blockIdx.x * 4 + w;
    const float4* xr = (const float4*)(X + (size_t)row * KDIM);
    float4 xv[3]; float s = 0.f, ss = 0.f;
#pragma unroll
    for (int i = 0; i < 3; ++i) {
        xv[i] = xr[lane + i * 64];
        s  += xv[i].x + xv[i].y + xv[i].z + xv[i].w;
        ss += xv[i].x * xv[i].x + xv[i].y * xv[i].y + xv[i].z * xv[i].z + xv[i].w * xv[i].w;
    }
    s = wave_sum(s); ss = wave_sum(ss);
    float m = s * (1.f / 768.f), var = ss * (1.f / 768.f) - m * m;
    float sa = rsqrtf(var + 1e-5f), ta = -m * sa;
#pragma unroll
    for (int i = 0; i < 3; ++i) {
        int idx = lane + i * 64;
        float4 gv = ((const float4*)g)[idx];
        float4 bv = ((const float4*)b)[idx];
        float a0 = fmaf(fmaf(xv[i].x, sa, ta), gv.x, bv.x);
        float a1 = fmaf(fmaf(xv[i].y, sa, ta), gv.y, bv.y);
        float a2 = fmaf(fmaf(xv[i].z, sa, ta), gv.z, bv.z);
        float a3 = fmaf(fmaf(xv[i].w, sa, ta), gv.w, bv.w);
        short h0 = f2bf(a0), h1 = f2bf(a1), h2 = f2bf(a2), h3 = f2bf(a3);
        ushort4 hv, lv;
        hv.x = (uint16_t)h0; hv.y = (uint16_t)h1; hv.z = (uint16_t)h2; hv.w = (uint16_t)h3;
        lv.x = (uint16_t)f2bf(a0 - bf2f(h0)); lv.y = (uint16_t)f2bf(a1 - bf2f(h1));
        lv.z = (uint16_t)f2bf(a2 - bf2f(h2)); lv.w = (uint16_t)f2bf(a3 - bf2f(h3));
        ((ushort4*)(Ah + (size_t)row * KDIM))[idx] = hv;
        ((ushort4*)(Al + (size_t)row * KDIM))[idx] = lv;
    }
}

// ---------------------------------------------------------------------------
// prep_A2: gate(tanh dot) + LN2 stats + affine + split.
// vp packed: hi bits in TOP half, lo bf16 in LOW half.
__global__ __launch_bounds__(256)
void prep_A2(const uint32_t* __restrict__ vp_hl, const float* __restrict__ qa_p,
             const float* __restrict__ g, const float* __restrict__ b,
             short* __restrict__ Ah, short* __restrict__ Al, int chunk_off)
{
    int w = threadIdx.x >> 6, lane = threadIdx.x & 63;
    int row = blockIdx.x * 4 + w;
    int bidx = (chunk_off + row) >> 5;
    const uint4*  hr = (const uint4*)(vp_hl + (size_t)row * KDIM);
    const float4* qr = (const float4*)(qa_p + (size_t)bidx * KDIM);
    float vp[12]; float s = 0.f, ss = 0.f, d = 0.f;
#pragma unroll
    for (int i = 0; i < 3; ++i) {
        uint4  uv = hr[lane + i * 64];
        float4 qv = qr[lane + i * 64];
        float v0 = asf(uv.x & 0xffff0000u) + asf(uv.x << 16);
        float v1 = asf(uv.y & 0xffff0000u) + asf(uv.y << 16);
        float v2 = asf(uv.z & 0xffff0000u) + asf(uv.z << 16);
        float v3 = asf(uv.w & 0xffff0000u) + asf(uv.w << 16);
        vp[i * 4 + 0] = v0; vp[i * 4 + 1] = v1; vp[i * 4 + 2] = v2; vp[i * 4 + 3] = v3;
        s  += v0 + v1 + v2 + v3;
        ss += v0 * v0 + v1 * v1 + v2 * v2 + v3 * v3;
        d  += v0 * qv.x + v1 * qv.y + v2 * qv.z + v3 * qv.w;
    }
    s = wave_sum(s); ss = wave_sum(ss); d = wave_sum(d);
    float gate = tanhf(d);
    float m = s * (1.f / 768.f), var = ss * (1.f / 768.f) - m * m;
    float den = rsqrtf(gate * gate * var + 1e-5f);
    float sa = gate * den, ta = -gate * m * den;
#pragma unroll
    for (int i = 0; i < 3; ++i) {
        int idx = lane + i * 64;
        float4 gv = ((const float4*)g)[idx];
        float4 bv = ((const float4*)b)[idx];
        float a0 = fmaf(fmaf(vp[i * 4 + 0], sa, ta), gv.x, bv.x);
        float a1 = fmaf(fmaf(vp[i * 4 + 1], sa, ta), gv.y, bv.y);
        float a2 = fmaf(fmaf(vp[i * 4 + 2], sa, ta), gv.z, bv.z);
        float a3 = fmaf(fmaf(vp[i * 4 + 3], sa, ta), gv.w, bv.w);
        short h0 = f2bf(a0), h1 = f2bf(a1), h2 = f2bf(a2), h3 = f2bf(a3);
        ushort4 hv, lv;
        hv.x = (uint16_t)h0; hv.y = (uint16_t)h1; hv.z = (uint16_t)h2; hv.w = (uint16_t)h3;
        lv.x = (uint16_t)f2bf(a0 - bf2f(h0)); lv.y = (uint16_t)f2bf(a1 - bf2f(h1));
        lv.z = (uint16_t)f2bf(a2 - bf2f(h2)); lv.w = (uint16_t)f2bf(a3 - bf2f(h3));
        ((ushort4*)(Ah + (size_t)row * KDIM))[idx] = hv;
        ((ushort4*)(Al + (size_t)row * KDIM))[idx] = lv;
    }
}

// ---------------------------------------------------------------------------
// prep_W: transpose + hi/lo split.  W[k][n] f32 -> Bh/Bl[n][k] bf16.
__global__ __launch_bounds__(256)
void prep_W(const float* __restrict__ W, short* __restrict__ Bh, short* __restrict__ Bl, int N)
{
    __shared__ float t[32][33];
    int bx = blockIdx.x, by = blockIdx.y;
    int lx = threadIdx.x & 31, ly = threadIdx.x >> 5;
#pragma unroll
    for (int r = 0; r < 32; r += 8)
        t[ly + r][lx] = W[(size_t)(by * 32 + ly + r) * N + bx * 32 + lx];
    __syncthreads();
#pragma unroll
    for (int r = 0; r < 32; r += 8) {
        float v = t[lx][ly + r];
        short hi = f2bf(v);
        size_t o = (size_t)(bx * 32 + ly + r) * KDIM + by * 32 + lx;
        Bh[o] = hi;
        Bl[o] = f2bf(v - bf2f(hi));
    }
}

// ---------------------------------------------------------------------------
// Split-bf16 MFMA GEMM: A via LDS (dbuf 2x16KB), B direct L2->VGPR dbuf.
// 256 thr / 4 waves (2x2), BM=BN=128, BK=32, 2 blocks/CU.
// Per k-tile: {8 ds_read A || 4 gl_lds A(kt+1) || 8 global B(kt+1)} ->
// VMW(12) -> lgkm -> 48 MFMA (AhBh,AhBl,AlBh) -> VMW(8) -> barrier.
//   MODE 0: out = gelu(.) packed (hi-bits | lo-bf16) u32 into 768-wide vp_hl.
//   MODE 1: partial row-dot with w2 -> partials[bx*2+wn][row].
#define VMW(N_) asm volatile("s_waitcnt vmcnt(" #N_ ")" ::: "memory")
#define SCB __builtin_amdgcn_sched_barrier(0)

#define STGA(KT_) do { char* db_ = lds + (((KT_) & 1) ? BUFSZ : 0);           \
    gl_lds16(sa[0] + (KT_) * 32, db_ + toff);                                 \
    gl_lds16(sa[1] + (KT_) * 32, db_ + 4096 + toff);                          \
    gl_lds16(sa[2] + (KT_) * 32, db_ + 8192 + toff);                          \
    gl_lds16(sa[3] + (KT_) * 32, db_ + 12288 + toff); } while (0)

#define LOADB(DST, KT_) do { _Pragma("unroll")                                \
    for (int j_ = 0; j_ < 8; ++j_)                                            \
        DST[j_] = *(const short8v*)(bp[j_] + (KT_) * 32); } while (0)

#define RDA(dst, BOFF) do { _Pragma("unroll")                                 \
    for (int mf = 0; mf < 4; ++mf) {                                          \
        int rA = wm * 64 + mf * 16 + lr;                                      \
        dst[mf] = *(const short8v*)(bb + (BOFF) + rA * 64 +                   \
                                    ((lh ^ ((rA >> 1) & 3)) << 4));           \
    } } while (0)

#define BODY(KT_, BCUR, BNXT, NL_) do {                                       \
    const char* bb = lds + (((KT_) & 1) ? BUFSZ : 0);                         \
    RDA(ah, 0); RDA(al, 8192);                                                \
    if (NL_) { STGA((KT_) + 1); }                                             \
    SCB;                                                                      \
    if (NL_) { LOADB(BNXT, (KT_) + 1); }                                      \
    SCB;                                                                      \
    if (NL_) { VMW(12); } else { VMW(0); }                                    \
    asm volatile("s_waitcnt lgkmcnt(0)" ::: "memory");                        \
    SCB;                                                                      \
    __builtin_amdgcn_s_setprio(1);                                            \
    _Pragma("unroll")                                                         \
    for (int mf = 0; mf < 4; ++mf)                                            \
        _Pragma("unroll")                                                     \
        for (int nf = 0; nf < 4; ++nf) {                                      \
            acc[mf][nf] = __builtin_amdgcn_mfma_f32_16x16x32_bf16(            \
                ah[mf], BCUR[nf], acc[mf][nf], 0, 0, 0);                      \
            acc[mf][nf] = __builtin_amdgcn_mfma_f32_16x16x32_bf16(            \
                ah[mf], BCUR[4 + nf], acc[mf][nf], 0, 0, 0);                  \
            acc[mf][nf] = __builtin_amdgcn_mfma_f32_16x16x32_bf16(            \
                al[mf], BCUR[nf], acc[mf][nf], 0, 0, 0);                      \
        }                                                                     \
    __builtin_amdgcn_s_setprio(0);                                            \
    SCB;                                                                      \
    if (NL_) { VMW(8); __builtin_amdgcn_s_barrier(); }                        \
} while (0)

template<int MODE>
__global__ __launch_bounds__(256, 2)
void gemm8(const short* __restrict__ Ah_g, const short* __restrict__ Al_g,
           const short* __restrict__ Bh_g, const short* __restrict__ Bl_g,
           const float* __restrict__ bias, uint32_t* __restrict__ O_hl,
           const float* __restrict__ w2, float* __restrict__ partials,
           int chunk_off)
{
    constexpr int BUFSZ = 16384;              // A-only buffer (Ah 8K + Al 8K)
    extern __shared__ __align__(16) char lds[];

    const int t = threadIdx.x;
    const int w = t >> 6, lane = t & 63;
    const int lr = lane & 15, lh = lane >> 4;
    const int wm = w >> 1, wn = w & 1;        // 2 x 2 wave grid

    const int gx = gridDim.x, nwg = gx * gridDim.y;
    int bidx = blockIdx.y * gx + blockIdx.x;
    int wid = (bidx & 7) * (nwg >> 3) + (bidx >> 3);
    const int bx = wid % gx, by = wid / gx;
    const int row0 = by * 128, col0 = bx * 128;

    // A stage source pointers (4 units of 64 rows; slot-XOR pre-swizzle).
    const int r_ = t >> 2, c_ = t & 3;
    const int swz_ = (c_ ^ ((r_ >> 1) & 3)) << 3;
    const int toff = t * 16;
    const short* sa[4];
    sa[0] = Ah_g + (size_t)(row0 + r_)      * KDIM + swz_;
    sa[1] = Ah_g + (size_t)(row0 + 64 + r_) * KDIM + swz_;
    sa[2] = Al_g + (size_t)(row0 + r_)      * KDIM + swz_;
    sa[3] = Al_g + (size_t)(row0 + 64 + r_) * KDIM + swz_;

    // B fragment global pointers: bh nf=0..3 then bl nf=0..3; 16B/lane each.
    const short* bp[8];
#pragma unroll
    for (int nf = 0; nf < 4; ++nf) {
        int n = col0 + wn * 64 + nf * 16 + lr;
        bp[nf]     = Bh_g + (size_t)n * KDIM + lh * 8;
        bp[4 + nf] = Bl_g + (size_t)n * KDIM + lh * 8;
    }

    f32x4 acc[4][4] = {};
    short8v ah[4], al[4];
    short8v bA[8], bB[8];                     // B register double-buffer

    // prologue: stage A(0), load B(0); wait A stages (4 oldest of 12); barrier
    STGA(0);
    SCB;
    LOADB(bA, 0);
    SCB;
    VMW(8);
    __builtin_amdgcn_s_barrier();

    for (int kt = 0; kt < 24; kt += 2) {
        BODY(kt,     bA, bB, true);
        BODY(kt + 1, bB, bA, (kt + 1 < 23));
    }

    if (MODE == 0) {
#pragma unroll
        for (int mf = 0; mf < 4; ++mf)
#pragma unroll
            for (int nf = 0; nf < 4; ++nf) {
                int n = col0 + wn * 64 + nf * 16 + lr;
                float bvs = bias[n];
#pragma unroll
                for (int q = 0; q < 4; ++q) {
                    int m = row0 + wm * 64 + mf * 16 + lh * 4 + q;
                    float gv = gelu_fast(acc[mf][nf][q] + bvs);
                    uint32_t u  = __builtin_bit_cast(uint32_t, gv);
                    uint32_t hb = u & 0xffff0000u;            // truncated hi
                    float rem   = gv - asf(hb);               // exact remainder
                    O_hl[(size_t)m * 768 + n] =
                        hb | (uint32_t)(uint16_t)f2bf(rem);   // hi TOP | lo LOW
                }
            }
    } else {
        float rs[4][4] = {};
#pragma unroll
        for (int mf = 0; mf < 4; ++mf)
#pragma unroll
            for (int nf = 0; nf < 4; ++nf) {
                int n = col0 + wn * 64 + nf * 16 + lr;
                float bvs = bias[n], wv = w2[n];
#pragma unroll
                for (int q = 0; q < 4; ++q)
                    rs[mf][q] += gelu_fast(acc[mf][nf][q] + bvs) * wv;
            }
#pragma unroll
        for (int mf = 0; mf < 4; ++mf)
#pragma unroll
            for (int q = 0; q < 4; ++q) {
                float vv = rs[mf][q];
                vv += __shfl_xor(vv, 1); vv += __shfl_xor(vv, 2);
                vv += __shfl_xor(vv, 4); vv += __shfl_xor(vv, 8);
                if (lr == 0) {
                    int m = chunk_off + row0 + wm * 64 + mf * 16 + lh * 4 + q;
                    partials[(size_t)(bx * 2 + wn) * 65536 + m] = vv;
                }
            }
    }
}

// ---------------------------------------------------------------------------
// f32 fallback GEMM for the small qa projection.
constexpr int BKF = 16;
__global__ __launch_bounds__(256)
void rowstats(const float* __restrict__ X, float2* __restrict__ st, int M)
{
    int wave = threadIdx.x >> 6, lane = threadIdx.x & 63;
    int row = blockIdx.x * 4 + wave;
    if (row >= M) return;
    const float4* xr = reinterpret_cast<const float4*>(X + (size_t)row * KDIM);
    float s = 0.f, ss = 0.f;
#pragma unroll
    for (int i = 0; i < 3; ++i) {
        float4 v = xr[lane + i * 64];
        s  += v.x + v.y + v.z + v.w;
        ss += v.x * v.x + v.y * v.y + v.z * v.z + v.w * v.w;
    }
    s = wave_sum(s); ss = wave_sum(ss);
    if (lane == 0) {
        float m = s * (1.0f / 768.0f);
        float var = ss * (1.0f / 768.0f) - m * m;
        float rstd = rsqrtf(var + 1e-5f);
        st[row] = make_float2(rstd, -m * rstd);
    }
}

template<int BM, int BN, int TM, int TN>
__global__ __launch_bounds__(256)
void gemm_fused(const float* __restrict__ X, const float2* __restrict__ st,
                const float* __restrict__ gw, const float* __restrict__ gb,
                const float* __restrict__ W, const float* __restrict__ bias,
                float* __restrict__ out, int M, int N)
{
    static_assert((BM / TM) * (BN / TN) == 256, "256 threads");
    __shared__ float As[BKF][BM];
    __shared__ float Bs[BKF][BN];
    const int t = threadIdx.x;
    constexpr int TXN = BN / TN;
    const int tx = t % TXN;
    const int ty = t / TXN;
    const int row0 = blockIdx.y * BM;
    const int col0 = blockIdx.x * BN;
    float acc[TM][TN] = {};
    constexpr int A_IT = BM * BKF / 4 / 256;
    constexpr int B_IT = BKF * BN / 4 / 256;
    for (int k0 = 0; k0 < KDIM; k0 += BKF) {
#pragma unroll
        for (int i = 0; i < A_IT; ++i) {
            int idx = t + i * 256;
            int r = idx >> 2;
            int c = (idx & 3) << 2;
            float4 xv = *reinterpret_cast<const float4*>(X + (size_t)(row0 + r) * KDIM + k0 + c);
            float2 s = st[row0 + r];
            float4 gv = *reinterpret_cast<const float4*>(gw + k0 + c);
            float4 bv = *reinterpret_cast<const float4*>(gb + k0 + c);
            As[c + 0][r] = fmaf(fmaf(xv.x, s.x, s.y), gv.x, bv.x);
            As[c + 1][r] = fmaf(fmaf(xv.y, s.x, s.y), gv.y, bv.y);
            As[c + 2][r] = fmaf(fmaf(xv.z, s.x, s.y), gv.z, bv.z);
            As[c + 3][r] = fmaf(fmaf(xv.w, s.x, s.y), gv.w, bv.w);
        }
#pragma unroll
        for (int i = 0; i < B_IT; ++i) {
            int idx = t + i * 256;
            int r = idx / (BN / 4);
            int c = (idx % (BN / 4)) << 2;
            *reinterpret_cast<float4*>(&Bs[r][c]) =
                *reinterpret_cast<const float4*>(W + (size_t)(k0 + r) * N + col0 + c);
        }
        __syncthreads();
#pragma unroll
        for (int kk = 0; kk < BKF; ++kk) {
            float a[TM], b[TN];
#pragma unroll
            for (int i = 0; i < TM; i += 4)
                *reinterpret_cast<float4*>(&a[i]) = *reinterpret_cast<const float4*>(&As[kk][ty * TM + i]);
#pragma unroll
            for (int j = 0; j < TN; j += 4)
                *reinterpret_cast<float4*>(&b[j]) = *reinterpret_cast<const float4*>(&Bs[kk][tx * TN + j]);
#pragma unroll
            for (int i = 0; i < TM; ++i)
#pragma unroll
                for (int j = 0; j < TN; ++j)
                    acc[i][j] = fmaf(a[i], b[j], acc[i][j]);
        }
        __syncthreads();
    }
#pragma unroll
    for (int i = 0; i < TM; ++i) {
        size_t row = row0 + ty * TM + i;
#pragma unroll
        for (int j = 0; j < TN; j += 4) {
            int col = col0 + tx * TN + j;
            float4 o;
            o.x = gelu_fast(acc[i][j + 0] + bias[col + 0]);
            o.y = gelu_fast(acc[i][j + 1] + bias[col + 1]);
            o.z = gelu_fast(acc[i][j + 2] + bias[col + 2]);
            o.w = gelu_fast(acc[i][j + 3] + bias[col + 3]);
            *reinterpret_cast<float4*>(out + row * N + col) = o;
        }
    }
}

// ---------------------------------------------------------------------------
// head: logits = sum(6 partials)+b2 -> softmax -> smooth -> softmax -> decode.
__global__ __launch_bounds__(64)
void head_kernel(const float* __restrict__ partials, const float* __restrict__ b2,
                 const float* __restrict__ sigma_p, float* __restrict__ out)
{
    int b = blockIdx.x, lane = threadIdx.x;
    __shared__ float ok[36];
    __shared__ float kg[32];
    __shared__ int sel[2];

    if (lane < 36) ok[lane] = 0.f;
    __syncthreads();

    float x = -3.4e38f;
    if (lane < 32) {
        int row = b * 32 + lane;
        x = b2[0];
#pragma unroll
        for (int p = 0; p < 6; ++p) x += partials[(size_t)p * 65536 + row];
    }
    float mx = wave_max(x);
    float e = (lane < 32) ? expf(x - mx) : 0.f;
    float sum = wave_sum(e);
    float ori = e / sum;
    if (lane < 32) {
        out[OFF_ORI + b * 32 + lane] = ori;
        ok[lane + 2] = ori;
    }
    __syncthreads();

    float sg = sigma_p[0];
    float kern[5]; float ks = 0.f;
#pragma unroll
    for (int k = 0; k < 5; ++k) { float xx = (float)(k - 2) / sg; kern[k] = expf(-0.5f * xx * xx); ks += kern[k]; }
    float sm = -3.4e38f;
    if (lane < 32) {
        sm = 0.f;
#pragma unroll
        for (int k = 0; k < 5; ++k) sm += (kern[k] / ks) * ok[lane + k];
    }
    float mx2 = wave_max(sm);
    float e2 = (lane < 32) ? expf(sm - mx2) : 0.f;
    float sum2 = wave_sum(e2);
    float kgv = e2 / sum2;
    if (lane < 32) {
        out[OFF_KG + b * 32 + lane] = kgv;
        kg[lane] = kgv;
    }
    __syncthreads();

    if (lane == 0) {
        int pm = 0; float bv = kg[0];
        for (int i = 1; i < 32; ++i) if (kg[i] > bv) { bv = kg[i]; pm = i; }
        float cum[33]; cum[0] = 0.f;
        for (int i = 0; i < 32; ++i) cum[i + 1] = cum[i] + kg[i];
        float bs = -3.4e38f; int bst = 0, ben = 0;
        const int wsz[3] = {1, 3, 5};
        for (int wi = 0; wi < 3; ++wi) {
            int w = wsz[wi];
            for (int s = 0; s + w <= 32; ++s) {
                if (pm >= s && pm < s + w) {
                    float sc = cum[s + w] - cum[s];
                    if (sc > bs) { bs = sc; bst = s; ben = s + w; }
                }
            }
        }
        out[OFF_MI + b * 2 + 0] = (float)bst;
        out[OFF_MI + b * 2 + 1] = (float)ben;
        out[OFF_ST + b] = (float)bst / 31.0f;
        out[OFF_ET + b] = (float)ben / 31.0f;
        sel[0] = bst; sel[1] = ben;
    }
    __syncthreads();
    if (lane < 32)
        out[OFF_MASK + b * 32 + lane] = (lane >= sel[0] && lane <= sel[1]) ? 1.0f : 0.0f;
}

// ---------------------------------------------------------------------------
extern "C" void kernel_launch(void* const* d_in, const int* in_sizes, int n_in,
                              void* d_out, int out_size, void* d_ws, size_t ws_size,
                              hipStream_t stream)
{
    const float* v      = (const float*)d_in[0];
    const float* qa     = (const float*)d_in[1];
    const float* vp_lng = (const float*)d_in[2];
    const float* vp_lnb = (const float*)d_in[3];
    const float* vp_w   = (const float*)d_in[4];
    const float* vp_b   = (const float*)d_in[5];
    const float* qp_lng = (const float*)d_in[6];
    const float* qp_lnb = (const float*)d_in[7];
    const float* qp_w   = (const float*)d_in[8];
    const float* qp_b   = (const float*)d_in[9];
    const float* g_lng  = (const float*)d_in[10];
    const float* g_lnb  = (const float*)d_in[11];
    const float* g_w1   = (const float*)d_in[12];
    const float* g_b1   = (const float*)d_in[13];
    const float* g_w2   = (const float*)d_in[14];
    const float* g_b2   = (const float*)d_in[15];
    const float* sigma  = (const float*)d_in[16];
    float* outf = (float*)d_out;

    // workspace layout (~213 MB)
    short* A1h = (short*)d_ws;                           // CHUNK*768
    short* A1l = A1h + (size_t)CHUNK * KDIM;
    uint32_t* vp_hl = (uint32_t*)(A1l + (size_t)CHUNK * KDIM);   // CHUNK*768 u32
    short* B1h = (short*)(vp_hl + (size_t)CHUNK * KDIM); // 768*768
    short* B1l = B1h + 768 * KDIM;
    short* B2h = B1l + 768 * KDIM;                       // 384*768
    short* B2l = B2h + 384 * KDIM;
    float* qa_p = (float*)(B2l + 384 * KDIM);            // 2048*768
    float* st_qa = qa_p + 2048 * KDIM;                   // 2048*2
    float* partials = st_qa + 4096;                      // 6*65536

    // qa path (small, f32 vector GEMM)
    rowstats<<<512, 256, 0, stream>>>(qa, (float2*)st_qa, 2048);
    gemm_fused<64, 64, 4, 4><<<dim3(12, 32), 256, 0, stream>>>(
        qa, (const float2*)st_qa, qp_lng, qp_lnb, qp_w, qp_b, qa_p, 2048, 768);

    // weight transpose + split
    prep_W<<<dim3(24, 24), 256, 0, stream>>>(vp_w, B1h, B1l, 768);
    prep_W<<<dim3(12, 24), 256, 0, stream>>>(g_w1, B2h, B2l, 384);

    constexpr int LDS8 = 32768;   // 2 bufs x 16 KB (A only) -> 2 blocks/CU

    for (int c = 0; c < 65536; c += CHUNK) {
        prep_A1<<<CHUNK / 4, 256, 0, stream>>>(v + (size_t)c * KDIM, vp_lng, vp_lnb, A1h, A1l);
        // v_p = gelu(A1 @ vp_w^T + vp_b): 128x128 tile, grid (6,256)=1536 blocks
        gemm8<0><<<dim3(6, CHUNK / 128), 256, LDS8, stream>>>(
            A1h, A1l, B1h, B1l, vp_b, vp_hl, nullptr, nullptr, 0);
        prep_A2<<<CHUNK / 4, 256, 0, stream>>>(vp_hl, qa_p, g_lng, g_lnb, A1h, A1l, c);
        // fused h@g_w1+gelu+dot(g_w2): 128x128 tile, grid (3,256)=768 blocks
        gemm8<1><<<dim3(3, CHUNK / 128), 256, LDS8, stream>>>(
            A1h, A1l, B2h, B2l, g_b1, nullptr, g_w2, partials, c);
    }

    head_kernel<<<2048, 64, 0, stream>>>(partials, g_b2, sigma, outf);
}

// Round 13
// 559.590 us; speedup vs baseline: 1.3360x; 1.3360x over previous
//
#include <hip/hip_runtime.h>
#include <math.h>
#include <stdint.h>

// ---------------------------------------------------------------------------
// GroundingModule — round 13: round-11 core (B via LDS, coalesced staging,
// 2 blocks/CU) with a SINGLE-PHASE k-loop:
//   STGA(kt+1) -> VMW(8) -> barrier_A -> 16 ds_read -> lgkm(0) -> barrier_B
//   -> 48 MFMA (one setprio cluster).
// Per k-tile: 2 barriers (was 6), 1 lgkm (was 3), 1 vmcnt (was 3).
// Fence proof: stage(kt+1) WAR-safe (buf[~kt] reads fenced by prev barrier_B);
// reads RAW-safe (own VMW(8) + barrier_A).  Round 12's uncoalesced B-in-reg
// reverted.  Epilogue: branchless gelu + truncated-hi split (round 11).
// ---------------------------------------------------------------------------

#define DEV __device__ __forceinline__

typedef __attribute__((ext_vector_type(8))) short short8v;   // 8 bf16
typedef __attribute__((ext_vector_type(4))) float f32x4;

constexpr int KDIM  = 768;
constexpr int CHUNK = 32768;

// output offsets (floats) in return order
constexpr int OFF_KG   = 0;
constexpr int OFF_MI   = 65536;
constexpr int OFF_ST   = 69632;
constexpr int OFF_ET   = 71680;
constexpr int OFF_MASK = 73728;
constexpr int OFF_ORI  = 139264;

DEV float wave_sum(float v) { for (int o = 32; o; o >>= 1) v += __shfl_xor(v, o); return v; }
DEV float wave_max(float v) { for (int o = 32; o; o >>= 1) v = fmaxf(v, __shfl_xor(v, o)); return v; }

// branchless gelu: 0.5x(1+erf(x/sqrt2)), erf via A&S 7.1.26 (|err|<=1.5e-7)
DEV float gelu_fast(float x) {
    float z = x * 0.70710678118654752f;
    float s = fabsf(z);
    float t = __builtin_amdgcn_rcpf(fmaf(0.3275911f, s, 1.0f));
    float p = t * fmaf(t, fmaf(t, fmaf(t, fmaf(t, 1.061405429f, -1.453152027f),
                                       1.421413741f), -0.284496736f), 0.254829592f);
    float e = __expf(-s * s);
    float er = copysignf(1.0f - p * e, z);
    return 0.5f * x * (1.0f + er);
}

DEV short f2bf(float x) {                       // f32 -> bf16 (RNE)
    uint32_t u = __builtin_bit_cast(uint32_t, x);
    u = u + 0x7fffu + ((u >> 16) & 1u);
    return (short)(u >> 16);
}
DEV float bf2f(short b) {
    uint32_t u = ((uint32_t)(uint16_t)b) << 16;
    return __builtin_bit_cast(float, u);
}
DEV float asf(uint32_t u) { return __builtin_bit_cast(float, u); }

DEV void gl_lds16(const void* g, void* l) {     // async 16B/lane global->LDS
    __builtin_amdgcn_global_load_lds(
        (const __attribute__((address_space(1))) uint32_t*)g,
        (__attribute__((address_space(3))) uint32_t*)l, 16, 0, 0);
}

// ---------------------------------------------------------------------------
// prep_A1: fused rowstats + LN-affine + hi/lo split.  One wave per row.
__global__ __launch_bounds__(256)
void prep_A1(const float* __restrict__ X, const float* __restrict__ g,
             const float* __restrict__ b, short* __restrict__ Ah, short* __restrict__ Al)
{
    int w = threadIdx.x >> 6, lane = threadIdx.x & 63;
    int row = blockIdx.x * 4 + w;
    const float4* xr = (const float4*)(X + (size_t)row * KDIM);
    float4 xv[3]; float s = 0.f, ss = 0.f;
#pragma unroll
    for (int i = 0; i < 3; ++i) {
        xv[i] = xr[lane + i * 64];
        s  += xv[i].x + xv[i].y + xv[i].z + xv[i].w;
        ss += xv[i].x * xv[i].x + xv[i].y * xv[i].y + xv[i].z * xv[i].z + xv[i].w * xv[i].w;
    }
    s = wave_sum(s); ss = wave_sum(ss);
    float m = s * (1.f / 768.f), var = ss * (1.f / 768.f) - m * m;
    float sa = rsqrtf(var + 1e-5f), ta = -m * sa;
#pragma unroll
    for (int i = 0; i < 3; ++i) {
        int idx = lane + i * 64;
        float4 gv = ((const float4*)g)[idx];
        float4 bv = ((const float4*)b)[idx];
        float a0 = fmaf(fmaf(xv[i].x, sa, ta), gv.x, bv.x);
        float a1 = fmaf(fmaf(xv[i].y, sa, ta), gv.y, bv.y);
        float a2 = fmaf(fmaf(xv[i].z, sa, ta), gv.z, bv.z);
        float a3 = fmaf(fmaf(xv[i].w, sa, ta), gv.w, bv.w);
        short h0 = f2bf(a0), h1 = f2bf(a1), h2 = f2bf(a2), h3 = f2bf(a3);
        ushort4 hv, lv;
        hv.x = (uint16_t)h0; hv.y = (uint16_t)h1; hv.z = (uint16_t)h2; hv.w = (uint16_t)h3;
        lv.x = (uint16_t)f2bf(a0 - bf2f(h0)); lv.y = (uint16_t)f2bf(a1 - bf2f(h1));
        lv.z = (uint16_t)f2bf(a2 - bf2f(h2)); lv.w = (uint16_t)f2bf(a3 - bf2f(h3));
        ((ushort4*)(Ah + (size_t)row * KDIM))[idx] = hv;
        ((ushort4*)(Al + (size_t)row * KDIM))[idx] = lv;
    }
}

// ---------------------------------------------------------------------------
// prep_A2: gate(tanh dot) + LN2 stats + affine + split.
// vp packed: hi bits in TOP half, lo bf16 in LOW half.
__global__ __launch_bounds__(256)
void prep_A2(const uint32_t* __restrict__ vp_hl, const float* __restrict__ qa_p,
             const float* __restrict__ g, const float* __restrict__ b,
             short* __restrict__ Ah, short* __restrict__ Al, int chunk_off)
{
    int w = threadIdx.x >> 6, lane = threadIdx.x & 63;
    int row = blockIdx.x * 4 + w;
    int bidx = (chunk_off + row) >> 5;
    const uint4*  hr = (const uint4*)(vp_hl + (size_t)row * KDIM);
    const float4* qr = (const float4*)(qa_p + (size_t)bidx * KDIM);
    float vp[12]; float s = 0.f, ss = 0.f, d = 0.f;
#pragma unroll
    for (int i = 0; i < 3; ++i) {
        uint4  uv = hr[lane + i * 64];
        float4 qv = qr[lane + i * 64];
        float v0 = asf(uv.x & 0xffff0000u) + asf(uv.x << 16);
        float v1 = asf(uv.y & 0xffff0000u) + asf(uv.y << 16);
        float v2 = asf(uv.z & 0xffff0000u) + asf(uv.z << 16);
        float v3 = asf(uv.w & 0xffff0000u) + asf(uv.w << 16);
        vp[i * 4 + 0] = v0; vp[i * 4 + 1] = v1; vp[i * 4 + 2] = v2; vp[i * 4 + 3] = v3;
        s  += v0 + v1 + v2 + v3;
        ss += v0 * v0 + v1 * v1 + v2 * v2 + v3 * v3;
        d  += v0 * qv.x + v1 * qv.y + v2 * qv.z + v3 * qv.w;
    }
    s = wave_sum(s); ss = wave_sum(ss); d = wave_sum(d);
    float gate = tanhf(d);
    float m = s * (1.f / 768.f), var = ss * (1.f / 768.f) - m * m;
    float den = rsqrtf(gate * gate * var + 1e-5f);
    float sa = gate * den, ta = -gate * m * den;
#pragma unroll
    for (int i = 0; i < 3; ++i) {
        int idx = lane + i * 64;
        float4 gv = ((const float4*)g)[idx];
        float4 bv = ((const float4*)b)[idx];
        float a0 = fmaf(fmaf(vp[i * 4 + 0], sa, ta), gv.x, bv.x);
        float a1 = fmaf(fmaf(vp[i * 4 + 1], sa, ta), gv.y, bv.y);
        float a2 = fmaf(fmaf(vp[i * 4 + 2], sa, ta), gv.z, bv.z);
        float a3 = fmaf(fmaf(vp[i * 4 + 3], sa, ta), gv.w, bv.w);
        short h0 = f2bf(a0), h1 = f2bf(a1), h2 = f2bf(a2), h3 = f2bf(a3);
        ushort4 hv, lv;
        hv.x = (uint16_t)h0; hv.y = (uint16_t)h1; hv.z = (uint16_t)h2; hv.w = (uint16_t)h3;
        lv.x = (uint16_t)f2bf(a0 - bf2f(h0)); lv.y = (uint16_t)f2bf(a1 - bf2f(h1));
        lv.z = (uint16_t)f2bf(a2 - bf2f(h2)); lv.w = (uint16_t)f2bf(a3 - bf2f(h3));
        ((ushort4*)(Ah + (size_t)row * KDIM))[idx] = hv;
        ((ushort4*)(Al + (size_t)row * KDIM))[idx] = lv;
    }
}

// ---------------------------------------------------------------------------
// prep_W: transpose + hi/lo split.  W[k][n] f32 -> Bh/Bl[n][k] bf16.
__global__ __launch_bounds__(256)
void prep_W(const float* __restrict__ W, short* __restrict__ Bh, short* __restrict__ Bl, int N)
{
    __shared__ float t[32][33];
    int bx = blockIdx.x, by = blockIdx.y;
    int lx = threadIdx.x & 31, ly = threadIdx.x >> 5;
#pragma unroll
    for (int r = 0; r < 32; r += 8)
        t[ly + r][lx] = W[(size_t)(by * 32 + ly + r) * N + bx * 32 + lx];
    __syncthreads();
#pragma unroll
    for (int r = 0; r < 32; r += 8) {
        float v = t[lx][ly + r];
        short hi = f2bf(v);
        size_t o = (size_t)(bx * 32 + ly + r) * KDIM + by * 32 + lx;
        Bh[o] = hi;
        Bl[o] = f2bf(v - bf2f(hi));
    }
}

// ---------------------------------------------------------------------------
// Split-bf16 MFMA GEMM, 2 blocks/CU.  256 thr / 4 waves (2x2), BM=BN=128,
// BK=32.  Single-phase k-loop (see header).  LDS buf (32KB):
// Ah@0(8K) Bh@8K(8K) Bl@16K(8K) Al@24K(8K); double-buffered.
// Unit order u0..u7 = Ah0,Ah1,Bh0,Bh1,Bl0,Bl1,Al0,Al1.
//   MODE 0: out = gelu(.) packed (hi-bits | lo-bf16) u32 into 768-wide vp_hl.
//   MODE 1: partial row-dot with w2 -> partials[bx*2+wn][row].
#define VMW(N_) asm volatile("s_waitcnt vmcnt(" #N_ ")" ::: "memory")
#define SCB __builtin_amdgcn_sched_barrier(0)

#define STG(G_, KT_) gl_lds16(sp[G_] + (KT_) * 32,                            \
    lds + (((KT_) & 1) ? BUFSZ : 0) + (G_) * 4096 + toff)

#define STGA8(KT_) do { STG(0, KT_); STG(1, KT_); STG(2, KT_); STG(3, KT_);   \
    STG(4, KT_); STG(5, KT_); STG(6, KT_); STG(7, KT_); } while (0)

#define RDA(dst, BOFF) do { _Pragma("unroll")                                 \
    for (int mf = 0; mf < 4; ++mf) {                                          \
        int rA = wm * 64 + mf * 16 + lr;                                      \
        dst[mf] = *(const short8v*)(bb + (BOFF) + rA * 64 +                   \
                                    ((lh ^ ((rA >> 1) & 3)) << 4));           \
    } } while (0)

#define RDB(dst, BOFF) do { _Pragma("unroll")                                 \
    for (int nf = 0; nf < 4; ++nf) {                                          \
        int rB = wn * 64 + nf * 16 + lr;                                      \
        dst[nf] = *(const short8v*)(bb + (BOFF) + rB * 64 +                   \
                                    ((lh ^ ((rB >> 1) & 3)) << 4));           \
    } } while (0)

#define BODY(KT_, NL_) do {                                                   \
    if (NL_) { STGA8((KT_) + 1); }                                            \
    SCB;                                                                      \
    if (NL_) { VMW(8); } else { VMW(0); }                                     \
    SCB;                                                                      \
    __builtin_amdgcn_s_barrier();            /* barrier_A: buf[KT_] staged */ \
    const char* bb = lds + (((KT_) & 1) ? BUFSZ : 0);                         \
    RDA(ah, 0); RDB(bh, 8192); RDB(bl, 16384); RDA(al, 24576);                \
    asm volatile("s_waitcnt lgkmcnt(0)" ::: "memory");                        \
    SCB;                                                                      \
    __builtin_amdgcn_s_barrier();            /* barrier_B: reads done */      \
    __builtin_amdgcn_s_setprio(1);                                            \
    _Pragma("unroll")                                                         \
    for (int mf = 0; mf < 4; ++mf)                                            \
        _Pragma("unroll")                                                     \
        for (int nf = 0; nf < 4; ++nf) {                                      \
            acc[mf][nf] = __builtin_amdgcn_mfma_f32_16x16x32_bf16(            \
                ah[mf], bh[nf], acc[mf][nf], 0, 0, 0);                        \
            acc[mf][nf] = __builtin_amdgcn_mfma_f32_16x16x32_bf16(            \
                ah[mf], bl[nf], acc[mf][nf], 0, 0, 0);                        \
            acc[mf][nf] = __builtin_amdgcn_mfma_f32_16x16x32_bf16(            \
                al[mf], bh[nf], acc[mf][nf], 0, 0, 0);                        \
        }                                                                     \
    __builtin_amdgcn_s_setprio(0);                                            \
    SCB;                                                                      \
} while (0)

template<int MODE>
__global__ __launch_bounds__(256, 2)
void gemm8(const short* __restrict__ Ah_g, const short* __restrict__ Al_g,
           const short* __restrict__ Bh_g, const short* __restrict__ Bl_g,
           const float* __restrict__ bias, uint32_t* __restrict__ O_hl,
           const float* __restrict__ w2, float* __restrict__ partials,
           int chunk_off)
{
    constexpr int BUFSZ = 32768;              // 32 KB per buffer
    extern __shared__ __align__(16) char lds[];

    const int t = threadIdx.x;
    const int w = t >> 6, lane = t & 63;
    const int lr = lane & 15, lh = lane >> 4;
    const int wm = w >> 1, wn = w & 1;        // 2 x 2 wave grid

    const int gx = gridDim.x, nwg = gx * gridDim.y;
    int bidx = blockIdx.y * gx + blockIdx.x;
    int wid = (bidx & 7) * (nwg >> 3) + (bidx >> 3);
    const int bx = wid % gx, by = wid / gx;
    const int row0 = by * 128, col0 = bx * 128;

    // stage source pointers (k=0); unit order Ah0,Ah1,Bh0,Bh1,Bl0,Bl1,Al0,Al1.
    // thread t covers (row r_ = t>>2, slot c_ = t&3) in a 64-row unit; source
    // k-chunk pre-swizzled c ^ ((r>>1)&3); LDS dest linear (unit*4K + t*16).
    const int r_ = t >> 2, c_ = t & 3;
    const int swz_ = (c_ ^ ((r_ >> 1) & 3)) << 3;
    const int toff = t * 16;
    const short* sp[8];
    sp[0] = Ah_g + (size_t)(row0 + r_)      * KDIM + swz_;
    sp[1] = Ah_g + (size_t)(row0 + 64 + r_) * KDIM + swz_;
    sp[2] = Bh_g + (size_t)(col0 + r_)      * KDIM + swz_;
    sp[3] = Bh_g + (size_t)(col0 + 64 + r_) * KDIM + swz_;
    sp[4] = Bl_g + (size_t)(col0 + r_)      * KDIM + swz_;
    sp[5] = Bl_g + (size_t)(col0 + 64 + r_) * KDIM + swz_;
    sp[6] = Al_g + (size_t)(row0 + r_)      * KDIM + swz_;
    sp[7] = Al_g + (size_t)(row0 + 64 + r_) * KDIM + swz_;

    f32x4 acc[4][4] = {};
    short8v ah[4], al[4], bh[4], bl[4];

    // prologue: stage k-tile 0 only; iter 0's VMW(8)+barrier_A covers it.
    STGA8(0);
    SCB;

    for (int kt = 0; kt < 24; kt += 2) {
        BODY(kt,     true);
        BODY(kt + 1, (kt + 1 < 23));
    }

    if (MODE == 0) {
#pragma unroll
        for (int mf = 0; mf < 4; ++mf)
#pragma unroll
            for (int nf = 0; nf < 4; ++nf) {
                int n = col0 + wn * 64 + nf * 16 + lr;
                float bvs = bias[n];
#pragma unroll
                for (int q = 0; q < 4; ++q) {
                    int m = row0 + wm * 64 + mf * 16 + lh * 4 + q;
                    float gv = gelu_fast(acc[mf][nf][q] + bvs);
                    uint32_t u  = __builtin_bit_cast(uint32_t, gv);
                    uint32_t hb = u & 0xffff0000u;            // truncated hi
                    float rem   = gv - asf(hb);               // exact remainder
                    O_hl[(size_t)m * 768 + n] =
                        hb | (uint32_t)(uint16_t)f2bf(rem);   // hi TOP | lo LOW
                }
            }
    } else {
        float rs[4][4] = {};
#pragma unroll
        for (int mf = 0; mf < 4; ++mf)
#pragma unroll
            for (int nf = 0; nf < 4; ++nf) {
                int n = col0 + wn * 64 + nf * 16 + lr;
                float bvs = bias[n], wv = w2[n];
#pragma unroll
                for (int q = 0; q < 4; ++q)
                    rs[mf][q] += gelu_fast(acc[mf][nf][q] + bvs) * wv;
            }
#pragma unroll
        for (int mf = 0; mf < 4; ++mf)
#pragma unroll
            for (int q = 0; q < 4; ++q) {
                float vv = rs[mf][q];
                vv += __shfl_xor(vv, 1); vv += __shfl_xor(vv, 2);
                vv += __shfl_xor(vv, 4); vv += __shfl_xor(vv, 8);
                if (lr == 0) {
                    int m = chunk_off + row0 + wm * 64 + mf * 16 + lh * 4 + q;
                    partials[(size_t)(bx * 2 + wn) * 65536 + m] = vv;
                }
            }
    }
}

// ---------------------------------------------------------------------------
// f32 fallback GEMM for the small qa projection.
constexpr int BKF = 16;
__global__ __launch_bounds__(256)
void rowstats(const float* __restrict__ X, float2* __restrict__ st, int M)
{
    int wave = threadIdx.x >> 6, lane = threadIdx.x & 63;
    int row = blockIdx.x * 4 + wave;
    if (row >= M) return;
    const float4* xr = reinterpret_cast<const float4*>(X + (size_t)row * KDIM);
    float s = 0.f, ss = 0.f;
#pragma unroll
    for (int i = 0; i < 3; ++i) {
        float4 v = xr[lane + i * 64];
        s  += v.x + v.y + v.z + v.w;
        ss += v.x * v.x + v.y * v.y + v.z * v.z + v.w * v.w;
    }
    s = wave_sum(s); ss = wave_sum(ss);
    if (lane == 0) {
        float m = s * (1.0f / 768.0f);
        float var = ss * (1.0f / 768.0f) - m * m;
        float rstd = rsqrtf(var + 1e-5f);
        st[row] = make_float2(rstd, -m * rstd);
    }
}

template<int BM, int BN, int TM, int TN>
__global__ __launch_bounds__(256)
void gemm_fused(const float* __restrict__ X, const float2* __restrict__ st,
                const float* __restrict__ gw, const float* __restrict__ gb,
                const float* __restrict__ W, const float* __restrict__ bias,
                float* __restrict__ out, int M, int N)
{
    static_assert((BM / TM) * (BN / TN) == 256, "256 threads");
    __shared__ float As[BKF][BM];
    __shared__ float Bs[BKF][BN];
    const int t = threadIdx.x;
    constexpr int TXN = BN / TN;
    const int tx = t % TXN;
    const int ty = t / TXN;
    const int row0 = blockIdx.y * BM;
    const int col0 = blockIdx.x * BN;
    float acc[TM][TN] = {};
    constexpr int A_IT = BM * BKF / 4 / 256;
    constexpr int B_IT = BKF * BN / 4 / 256;
    for (int k0 = 0; k0 < KDIM; k0 += BKF) {
#pragma unroll
        for (int i = 0; i < A_IT; ++i) {
            int idx = t + i * 256;
            int r = idx >> 2;
            int c = (idx & 3) << 2;
            float4 xv = *reinterpret_cast<const float4*>(X + (size_t)(row0 + r) * KDIM + k0 + c);
            float2 s = st[row0 + r];
            float4 gv = *reinterpret_cast<const float4*>(gw + k0 + c);
            float4 bv = *reinterpret_cast<const float4*>(gb + k0 + c);
            As[c + 0][r] = fmaf(fmaf(xv.x, s.x, s.y), gv.x, bv.x);
            As[c + 1][r] = fmaf(fmaf(xv.y, s.x, s.y), gv.y, bv.y);
            As[c + 2][r] = fmaf(fmaf(xv.z, s.x, s.y), gv.z, bv.z);
            As[c + 3][r] = fmaf(fmaf(xv.w, s.x, s.y), gv.w, bv.w);
        }
#pragma unroll
        for (int i = 0; i < B_IT; ++i) {
            int idx = t + i * 256;
            int r = idx / (BN / 4);
            int c = (idx % (BN / 4)) << 2;
            *reinterpret_cast<float4*>(&Bs[r][c]) =
                *reinterpret_cast<const float4*>(W + (size_t)(k0 + r) * N + col0 + c);
        }
        __syncthreads();
#pragma unroll
        for (int kk = 0; kk < BKF; ++kk) {
            float a[TM], b[TN];
#pragma unroll
            for (int i = 0; i < TM; i += 4)
                *reinterpret_cast<float4*>(&a[i]) = *reinterpret_cast<const float4*>(&As[kk][ty * TM + i]);
#pragma unroll
            for (int j = 0; j < TN; j += 4)
                *reinterpret_cast<float4*>(&b[j]) = *reinterpret_cast<const float4*>(&Bs[kk][tx * TN + j]);
#pragma unroll
            for (int i = 0; i < TM; ++i)
#pragma unroll
                for (int j = 0; j < TN; ++j)
                    acc[i][j] = fmaf(a[i], b[j], acc[i][j]);
        }
        __syncthreads();
    }
#pragma unroll
    for (int i = 0; i < TM; ++i) {
        size_t row = row0 + ty * TM + i;
#pragma unroll
        for (int j = 0; j < TN; j += 4) {
            int col = col0 + tx * TN + j;
            float4 o;
            o.x = gelu_fast(acc[i][j + 0] + bias[col + 0]);
            o.y = gelu_fast(acc[i][j + 1] + bias[col + 1]);
            o.z = gelu_fast(acc[i][j + 2] + bias[col + 2]);
            o.w = gelu_fast(acc[i][j + 3] + bias[col + 3]);
            *reinterpret_cast<float4*>(out + row * N + col) = o;
        }
    }
}

// ---------------------------------------------------------------------------
// head: logits = sum(6 partials)+b2 -> softmax -> smooth -> softmax -> decode.
__global__ __launch_bounds__(64)
void head_kernel(const float* __restrict__ partials, const float* __restrict__ b2,
                 const float* __restrict__ sigma_p, float* __restrict__ out)
{
    int b = blockIdx.x, lane = threadIdx.x;
    __shared__ float ok[36];
    __shared__ float kg[32];
    __shared__ int sel[2];

    if (lane < 36) ok[lane] = 0.f;
    __syncthreads();

    float x = -3.4e38f;
    if (lane < 32) {
        int row = b * 32 + lane;
        x = b2[0];
#pragma unroll
        for (int p = 0; p < 6; ++p) x += partials[(size_t)p * 65536 + row];
    }
    float mx = wave_max(x);
    float e = (lane < 32) ? expf(x - mx) : 0.f;
    float sum = wave_sum(e);
    float ori = e / sum;
    if (lane < 32) {
        out[OFF_ORI + b * 32 + lane] = ori;
        ok[lane + 2] = ori;
    }
    __syncthreads();

    float sg = sigma_p[0];
    float kern[5]; float ks = 0.f;
#pragma unroll
    for (int k = 0; k < 5; ++k) { float xx = (float)(k - 2) / sg; kern[k] = expf(-0.5f * xx * xx); ks += kern[k]; }
    float sm = -3.4e38f;
    if (lane < 32) {
        sm = 0.f;
#pragma unroll
        for (int k = 0; k < 5; ++k) sm += (kern[k] / ks) * ok[lane + k];
    }
    float mx2 = wave_max(sm);
    float e2 = (lane < 32) ? expf(sm - mx2) : 0.f;
    float sum2 = wave_sum(e2);
    float kgv = e2 / sum2;
    if (lane < 32) {
        out[OFF_KG + b * 32 + lane] = kgv;
        kg[lane] = kgv;
    }
    __syncthreads();

    if (lane == 0) {
        int pm = 0; float bv = kg[0];
        for (int i = 1; i < 32; ++i) if (kg[i] > bv) { bv = kg[i]; pm = i; }
        float cum[33]; cum[0] = 0.f;
        for (int i = 0; i < 32; ++i) cum[i + 1] = cum[i] + kg[i];
        float bs = -3.4e38f; int bst = 0, ben = 0;
        const int wsz[3] = {1, 3, 5};
        for (int wi = 0; wi < 3; ++wi) {
            int w = wsz[wi];
            for (int s = 0; s + w <= 32; ++s) {
                if (pm >= s && pm < s + w) {
                    float sc = cum[s + w] - cum[s];
                    if (sc > bs) { bs = sc; bst = s; ben = s + w; }
                }
            }
        }
        out[OFF_MI + b * 2 + 0] = (float)bst;
        out[OFF_MI + b * 2 + 1] = (float)ben;
        out[OFF_ST + b] = (float)bst / 31.0f;
        out[OFF_ET + b] = (float)ben / 31.0f;
        sel[0] = bst; sel[1] = ben;
    }
    __syncthreads();
    if (lane < 32)
        out[OFF_MASK + b * 32 + lane] = (lane >= sel[0] && lane <= sel[1]) ? 1.0f : 0.0f;
}

// ---------------------------------------------------------------------------
extern "C" void kernel_launch(void* const* d_in, const int* in_sizes, int n_in,
                              void* d_out, int out_size, void* d_ws, size_t ws_size,
                              hipStream_t stream)
{
    const float* v      = (const float*)d_in[0];
    const float* qa     = (const float*)d_in[1];
    const float* vp_lng = (const float*)d_in[2];
    const float* vp_lnb = (const float*)d_in[3];
    const float* vp_w   = (const float*)d_in[4];
    const float* vp_b   = (const float*)d_in[5];
    const float* qp_lng = (const float*)d_in[6];
    const float* qp_lnb = (const float*)d_in[7];
    const float* qp_w   = (const float*)d_in[8];
    const float* qp_b   = (const float*)d_in[9];
    const float* g_lng  = (const float*)d_in[10];
    const float* g_lnb  = (const float*)d_in[11];
    const float* g_w1   = (const float*)d_in[12];
    const float* g_b1   = (const float*)d_in[13];
    const float* g_w2   = (const float*)d_in[14];
    const float* g_b2   = (const float*)d_in[15];
    const float* sigma  = (const float*)d_in[16];
    float* outf = (float*)d_out;

    // workspace layout (~213 MB)
    short* A1h = (short*)d_ws;                           // CHUNK*768
    short* A1l = A1h + (size_t)CHUNK * KDIM;
    uint32_t* vp_hl = (uint32_t*)(A1l + (size_t)CHUNK * KDIM);   // CHUNK*768 u32
    short* B1h = (short*)(vp_hl + (size_t)CHUNK * KDIM); // 768*768
    short* B1l = B1h + 768 * KDIM;
    short* B2h = B1l + 768 * KDIM;                       // 384*768
    short* B2l = B2h + 384 * KDIM;
    float* qa_p = (float*)(B2l + 384 * KDIM);            // 2048*768
    float* st_qa = qa_p + 2048 * KDIM;                   // 2048*2
    float* partials = st_qa + 4096;                      // 6*65536

    // qa path (small, f32 vector GEMM)
    rowstats<<<512, 256, 0, stream>>>(qa, (float2*)st_qa, 2048);
    gemm_fused<64, 64, 4, 4><<<dim3(12, 32), 256, 0, stream>>>(
        qa, (const float2*)st_qa, qp_lng, qp_lnb, qp_w, qp_b, qa_p, 2048, 768);

    // weight transpose + split
    prep_W<<<dim3(24, 24), 256, 0, stream>>>(vp_w, B1h, B1l, 768);
    prep_W<<<dim3(12, 24), 256, 0, stream>>>(g_w1, B2h, B2l, 384);

    constexpr int LDS8 = 65536;   // 2 bufs x 32 KB -> 2 blocks/CU

    for (int c = 0; c < 65536; c += CHUNK) {
        prep_A1<<<CHUNK / 4, 256, 0, stream>>>(v + (size_t)c * KDIM, vp_lng, vp_lnb, A1h, A1l);
        // v_p = gelu(A1 @ vp_w^T + vp_b): 128x128 tile, grid (6,256)=1536 blocks
        gemm8<0><<<dim3(6, CHUNK / 128), 256, LDS8, stream>>>(
            A1h, A1l, B1h, B1l, vp_b, vp_hl, nullptr, nullptr, 0);
        prep_A2<<<CHUNK / 4, 256, 0, stream>>>(vp_hl, qa_p, g_lng, g_lnb, A1h, A1l, c);
        // fused h@g_w1+gelu+dot(g_w2): 128x128 tile, grid (3,256)=768 blocks
        gemm8<1><<<dim3(3, CHUNK / 128), 256, LDS8, stream>>>(
            A1h, A1l, B2h, B2l, g_b1, nullptr, g_w2, partials, c);
    }

    head_kernel<<<2048, 64, 0, stream>>>(partials, g_b2, sigma, outf);
}

// Round 14
// 538.920 us; speedup vs baseline: 1.3873x; 1.0384x over previous
//
#include <hip/hip_runtime.h>
#include <math.h>
#include <stdint.h>

// ---------------------------------------------------------------------------
// GroundingModule — round 14: round-13 single-phase loop, BN widened to 192.
//   MODE0 (N=768): grid (4,256)=1024 = 2 clean CU-rounds (was 3).
//   MODE1 (N=384): grid (2,256)=512  = 1 clean CU-round  (was 2 for half work).
// Per k-tile: stage 10x4KB units -> VMW(10) -> barrier -> 20 ds_read ->
// lgkm(0) -> barrier -> 72 MFMA (setprio cluster).  LDS 2x40KB = 80KB ->
// still 2 blocks/CU.  Epilogue: branchless gelu + truncated-hi split.
// ---------------------------------------------------------------------------

#define DEV __device__ __forceinline__

typedef __attribute__((ext_vector_type(8))) short short8v;   // 8 bf16
typedef __attribute__((ext_vector_type(4))) float f32x4;

constexpr int KDIM  = 768;
constexpr int CHUNK = 32768;

// output offsets (floats) in return order
constexpr int OFF_KG   = 0;
constexpr int OFF_MI   = 65536;
constexpr int OFF_ST   = 69632;
constexpr int OFF_ET   = 71680;
constexpr int OFF_MASK = 73728;
constexpr int OFF_ORI  = 139264;

DEV float wave_sum(float v) { for (int o = 32; o; o >>= 1) v += __shfl_xor(v, o); return v; }
DEV float wave_max(float v) { for (int o = 32; o; o >>= 1) v = fmaxf(v, __shfl_xor(v, o)); return v; }

// branchless gelu: 0.5x(1+erf(x/sqrt2)), erf via A&S 7.1.26 (|err|<=1.5e-7)
DEV float gelu_fast(float x) {
    float z = x * 0.70710678118654752f;
    float s = fabsf(z);
    float t = __builtin_amdgcn_rcpf(fmaf(0.3275911f, s, 1.0f));
    float p = t * fmaf(t, fmaf(t, fmaf(t, fmaf(t, 1.061405429f, -1.453152027f),
                                       1.421413741f), -0.284496736f), 0.254829592f);
    float e = __expf(-s * s);
    float er = copysignf(1.0f - p * e, z);
    return 0.5f * x * (1.0f + er);
}

DEV short f2bf(float x) {                       // f32 -> bf16 (RNE)
    uint32_t u = __builtin_bit_cast(uint32_t, x);
    u = u + 0x7fffu + ((u >> 16) & 1u);
    return (short)(u >> 16);
}
DEV float bf2f(short b) {
    uint32_t u = ((uint32_t)(uint16_t)b) << 16;
    return __builtin_bit_cast(float, u);
}
DEV float asf(uint32_t u) { return __builtin_bit_cast(float, u); }

DEV void gl_lds16(const void* g, void* l) {     // async 16B/lane global->LDS
    __builtin_amdgcn_global_load_lds(
        (const __attribute__((address_space(1))) uint32_t*)g,
        (__attribute__((address_space(3))) uint32_t*)l, 16, 0, 0);
}

// ---------------------------------------------------------------------------
// prep_A1: fused rowstats + LN-affine + hi/lo split.  One wave per row.
__global__ __launch_bounds__(256)
void prep_A1(const float* __restrict__ X, const float* __restrict__ g,
             const float* __restrict__ b, short* __restrict__ Ah, short* __restrict__ Al)
{
    int w = threadIdx.x >> 6, lane = threadIdx.x & 63;
    int row = blockIdx.x * 4 + w;
    const float4* xr = (const float4*)(X + (size_t)row * KDIM);
    float4 xv[3]; float s = 0.f, ss = 0.f;
#pragma unroll
    for (int i = 0; i < 3; ++i) {
        xv[i] = xr[lane + i * 64];
        s  += xv[i].x + xv[i].y + xv[i].z + xv[i].w;
        ss += xv[i].x * xv[i].x + xv[i].y * xv[i].y + xv[i].z * xv[i].z + xv[i].w * xv[i].w;
    }
    s = wave_sum(s); ss = wave_sum(ss);
    float m = s * (1.f / 768.f), var = ss * (1.f / 768.f) - m * m;
    float sa = rsqrtf(var + 1e-5f), ta = -m * sa;
#pragma unroll
    for (int i = 0; i < 3; ++i) {
        int idx = lane + i * 64;
        float4 gv = ((const float4*)g)[idx];
        float4 bv = ((const float4*)b)[idx];
        float a0 = fmaf(fmaf(xv[i].x, sa, ta), gv.x, bv.x);
        float a1 = fmaf(fmaf(xv[i].y, sa, ta), gv.y, bv.y);
        float a2 = fmaf(fmaf(xv[i].z, sa, ta), gv.z, bv.z);
        float a3 = fmaf(fmaf(xv[i].w, sa, ta), gv.w, bv.w);
        short h0 = f2bf(a0), h1 = f2bf(a1), h2 = f2bf(a2), h3 = f2bf(a3);
        ushort4 hv, lv;
        hv.x = (uint16_t)h0; hv.y = (uint16_t)h1; hv.z = (uint16_t)h2; hv.w = (uint16_t)h3;
        lv.x = (uint16_t)f2bf(a0 - bf2f(h0)); lv.y = (uint16_t)f2bf(a1 - bf2f(h1));
        lv.z = (uint16_t)f2bf(a2 - bf2f(h2)); lv.w = (uint16_t)f2bf(a3 - bf2f(h3));
        ((ushort4*)(Ah + (size_t)row * KDIM))[idx] = hv;
        ((ushort4*)(Al + (size_t)row * KDIM))[idx] = lv;
    }
}

// ---------------------------------------------------------------------------
// prep_A2: gate(tanh dot) + LN2 stats + affine + split.
// vp packed: hi bits in TOP half, lo bf16 in LOW half.
__global__ __launch_bounds__(256)
void prep_A2(const uint32_t* __restrict__ vp_hl, const float* __restrict__ qa_p,
             const float* __restrict__ g, const float* __restrict__ b,
             short* __restrict__ Ah, short* __restrict__ Al, int chunk_off)
{
    int w = threadIdx.x >> 6, lane = threadIdx.x & 63;
    int row = blockIdx.x * 4 + w;
    int bidx = (chunk_off + row) >> 5;
    const uint4*  hr = (const uint4*)(vp_hl + (size_t)row * KDIM);
    const float4* qr = (const float4*)(qa_p + (size_t)bidx * KDIM);
    float vp[12]; float s = 0.f, ss = 0.f, d = 0.f;
#pragma unroll
    for (int i = 0; i < 3; ++i) {
        uint4  uv = hr[lane + i * 64];
        float4 qv = qr[lane + i * 64];
        float v0 = asf(uv.x & 0xffff0000u) + asf(uv.x << 16);
        float v1 = asf(uv.y & 0xffff0000u) + asf(uv.y << 16);
        float v2 = asf(uv.z & 0xffff0000u) + asf(uv.z << 16);
        float v3 = asf(uv.w & 0xffff0000u) + asf(uv.w << 16);
        vp[i * 4 + 0] = v0; vp[i * 4 + 1] = v1; vp[i * 4 + 2] = v2; vp[i * 4 + 3] = v3;
        s  += v0 + v1 + v2 + v3;
        ss += v0 * v0 + v1 * v1 + v2 * v2 + v3 * v3;
        d  += v0 * qv.x + v1 * qv.y + v2 * qv.z + v3 * qv.w;
    }
    s = wave_sum(s); ss = wave_sum(ss); d = wave_sum(d);
    float gate = tanhf(d);
    float m = s * (1.f / 768.f), var = ss * (1.f / 768.f) - m * m;
    float den = rsqrtf(gate * gate * var + 1e-5f);
    float sa = gate * den, ta = -gate * m * den;
#pragma unroll
    for (int i = 0; i < 3; ++i) {
        int idx = lane + i * 64;
        float4 gv = ((const float4*)g)[idx];
        float4 bv = ((const float4*)b)[idx];
        float a0 = fmaf(fmaf(vp[i * 4 + 0], sa, ta), gv.x, bv.x);
        float a1 = fmaf(fmaf(vp[i * 4 + 1], sa, ta), gv.y, bv.y);
        float a2 = fmaf(fmaf(vp[i * 4 + 2], sa, ta), gv.z, bv.z);
        float a3 = fmaf(fmaf(vp[i * 4 + 3], sa, ta), gv.w, bv.w);
        short h0 = f2bf(a0), h1 = f2bf(a1), h2 = f2bf(a2), h3 = f2bf(a3);
        ushort4 hv, lv;
        hv.x = (uint16_t)h0; hv.y = (uint16_t)h1; hv.z = (uint16_t)h2; hv.w = (uint16_t)h3;
        lv.x = (uint16_t)f2bf(a0 - bf2f(h0)); lv.y = (uint16_t)f2bf(a1 - bf2f(h1));
        lv.z = (uint16_t)f2bf(a2 - bf2f(h2)); lv.w = (uint16_t)f2bf(a3 - bf2f(h3));
        ((ushort4*)(Ah + (size_t)row * KDIM))[idx] = hv;
        ((ushort4*)(Al + (size_t)row * KDIM))[idx] = lv;
    }
}

// ---------------------------------------------------------------------------
// prep_W: transpose + hi/lo split.  W[k][n] f32 -> Bh/Bl[n][k] bf16.
__global__ __launch_bounds__(256)
void prep_W(const float* __restrict__ W, short* __restrict__ Bh, short* __restrict__ Bl, int N)
{
    __shared__ float t[32][33];
    int bx = blockIdx.x, by = blockIdx.y;
    int lx = threadIdx.x & 31, ly = threadIdx.x >> 5;
#pragma unroll
    for (int r = 0; r < 32; r += 8)
        t[ly + r][lx] = W[(size_t)(by * 32 + ly + r) * N + bx * 32 + lx];
    __syncthreads();
#pragma unroll
    for (int r = 0; r < 32; r += 8) {
        float v = t[lx][ly + r];
        short hi = f2bf(v);
        size_t o = (size_t)(bx * 32 + ly + r) * KDIM + by * 32 + lx;
        Bh[o] = hi;
        Bl[o] = f2bf(v - bf2f(hi));
    }
}

// ---------------------------------------------------------------------------
// Split-bf16 MFMA GEMM, 2 blocks/CU.  256 thr / 4 waves (2x2), BM=128 BN=192,
// BK=32.  Single-phase k-loop.  LDS buf (40KB): Ah@0(8K) Al@8K(8K)
// Bh@16K(12K) Bl@28K(12K); double-buffered (80KB).
// Units u0..u9 = Ah0,Ah1,Al0,Al1,Bh0,Bh1,Bh2,Bl0,Bl1,Bl2 (4KB each).
//   MODE 0: out = gelu(.) packed (hi-bits | lo-bf16) u32 into 768-wide vp_hl.
//   MODE 1: partial row-dot with w2 -> partials[bx*2+wn][row] (4 partials).
#define VMW(N_) asm volatile("s_waitcnt vmcnt(" #N_ ")" ::: "memory")
#define SCB __builtin_amdgcn_sched_barrier(0)

#define STG(G_, KT_) gl_lds16(sp[G_] + (KT_) * 32,                            \
    lds + (((KT_) & 1) ? BUFSZ : 0) + (G_) * 4096 + toff)

#define STGA10(KT_) do { STG(0, KT_); STG(1, KT_); STG(2, KT_); STG(3, KT_);  \
    STG(4, KT_); STG(5, KT_); STG(6, KT_); STG(7, KT_); STG(8, KT_);          \
    STG(9, KT_); } while (0)

#define RDA(dst, BOFF) do { _Pragma("unroll")                                 \
    for (int mf = 0; mf < 4; ++mf) {                                          \
        int rA = wm * 64 + mf * 16 + lr;                                      \
        dst[mf] = *(const short8v*)(bb + (BOFF) + rA * 64 +                   \
                                    ((lh ^ ((rA >> 1) & 3)) << 4));           \
    } } while (0)

#define RDB(dst, BOFF) do { _Pragma("unroll")                                 \
    for (int nf = 0; nf < 6; ++nf) {                                          \
        int rB = wn * 96 + nf * 16 + lr;                                      \
        dst[nf] = *(const short8v*)(bb + (BOFF) + rB * 64 +                   \
                                    ((lh ^ ((rB >> 1) & 3)) << 4));           \
    } } while (0)

#define BODY(KT_, NL_) do {                                                   \
    if (NL_) { STGA10((KT_) + 1); }                                           \
    SCB;                                                                      \
    if (NL_) { VMW(10); } else { VMW(0); }                                    \
    SCB;                                                                      \
    __builtin_amdgcn_s_barrier();            /* buf[KT_] staged for all */    \
    const char* bb = lds + (((KT_) & 1) ? BUFSZ : 0);                         \
    RDA(ah, 0); RDA(al, 8192); RDB(bh, 16384); RDB(bl, 28672);                \
    asm volatile("s_waitcnt lgkmcnt(0)" ::: "memory");                        \
    SCB;                                                                      \
    __builtin_amdgcn_s_barrier();            /* reads done for all */         \
    __builtin_amdgcn_s_setprio(1);                                            \
    _Pragma("unroll")                                                         \
    for (int mf = 0; mf < 4; ++mf)                                            \
        _Pragma("unroll")                                                     \
        for (int nf = 0; nf < 6; ++nf) {                                      \
            acc[mf][nf] = __builtin_amdgcn_mfma_f32_16x16x32_bf16(            \
                ah[mf], bh[nf], acc[mf][nf], 0, 0, 0);                        \
            acc[mf][nf] = __builtin_amdgcn_mfma_f32_16x16x32_bf16(            \
                ah[mf], bl[nf], acc[mf][nf], 0, 0, 0);                        \
            acc[mf][nf] = __builtin_amdgcn_mfma_f32_16x16x32_bf16(            \
                al[mf], bh[nf], acc[mf][nf], 0, 0, 0);                        \
        }                                                                     \
    __builtin_amdgcn_s_setprio(0);                                            \
    SCB;                                                                      \
} while (0)

template<int MODE>
__global__ __launch_bounds__(256, 2)
void gemm8(const short* __restrict__ Ah_g, const short* __restrict__ Al_g,
           const short* __restrict__ Bh_g, const short* __restrict__ Bl_g,
           const float* __restrict__ bias, uint32_t* __restrict__ O_hl,
           const float* __restrict__ w2, float* __restrict__ partials,
           int chunk_off)
{
    constexpr int BUFSZ = 40960;              // 40 KB per buffer
    extern __shared__ __align__(16) char lds[];

    const int t = threadIdx.x;
    const int w = t >> 6, lane = t & 63;
    const int lr = lane & 15, lh = lane >> 4;
    const int wm = w >> 1, wn = w & 1;        // 2 x 2 wave grid

    const int gx = gridDim.x, nwg = gx * gridDim.y;
    int bidx = blockIdx.y * gx + blockIdx.x;
    int wid = (bidx & 7) * (nwg >> 3) + (bidx >> 3);
    const int bx = wid % gx, by = wid / gx;
    const int row0 = by * 128, col0 = bx * 192;

    // stage source pointers (k=0); thread t covers (row r_ = t>>2 in its
    // 64-row unit, slot c_ = t&3); source k-chunk pre-swizzled c^((r>>1)&3);
    // LDS dest linear (unit*4K + t*16).
    const int r_ = t >> 2, c_ = t & 3;
    const int swz_ = (c_ ^ ((r_ >> 1) & 3)) << 3;
    const int toff = t * 16;
    const short* sp[10];
    sp[0] = Ah_g + (size_t)(row0 + r_)       * KDIM + swz_;
    sp[1] = Ah_g + (size_t)(row0 + 64 + r_)  * KDIM + swz_;
    sp[2] = Al_g + (size_t)(row0 + r_)       * KDIM + swz_;
    sp[3] = Al_g + (size_t)(row0 + 64 + r_)  * KDIM + swz_;
    sp[4] = Bh_g + (size_t)(col0 + r_)       * KDIM + swz_;
    sp[5] = Bh_g + (size_t)(col0 + 64 + r_)  * KDIM + swz_;
    sp[6] = Bh_g + (size_t)(col0 + 128 + r_) * KDIM + swz_;
    sp[7] = Bl_g + (size_t)(col0 + r_)       * KDIM + swz_;
    sp[8] = Bl_g + (size_t)(col0 + 64 + r_)  * KDIM + swz_;
    sp[9] = Bl_g + (size_t)(col0 + 128 + r_) * KDIM + swz_;

    f32x4 acc[4][6] = {};
    short8v ah[4], al[4], bh[6], bl[6];

    // prologue: stage k-tile 0 only; iter 0's VMW(10)+barrier covers it.
    STGA10(0);
    SCB;

    for (int kt = 0; kt < 24; kt += 2) {
        BODY(kt,     true);
        BODY(kt + 1, (kt + 1 < 23));
    }

    if (MODE == 0) {
#pragma unroll
        for (int mf = 0; mf < 4; ++mf)
#pragma unroll
            for (int nf = 0; nf < 6; ++nf) {
                int n = col0 + wn * 96 + nf * 16 + lr;
                float bvs = bias[n];
#pragma unroll
                for (int q = 0; q < 4; ++q) {
                    int m = row0 + wm * 64 + mf * 16 + lh * 4 + q;
                    float gv = gelu_fast(acc[mf][nf][q] + bvs);
                    uint32_t u  = __builtin_bit_cast(uint32_t, gv);
                    uint32_t hb = u & 0xffff0000u;            // truncated hi
                    float rem   = gv - asf(hb);               // exact remainder
                    O_hl[(size_t)m * 768 + n] =
                        hb | (uint32_t)(uint16_t)f2bf(rem);   // hi TOP | lo LOW
                }
            }
    } else {
        float rs[4][4] = {};
#pragma unroll
        for (int mf = 0; mf < 4; ++mf)
#pragma unroll
            for (int nf = 0; nf < 6; ++nf) {
                int n = col0 + wn * 96 + nf * 16 + lr;
                float bvs = bias[n], wv = w2[n];
#pragma unroll
                for (int q = 0; q < 4; ++q)
                    rs[mf][q] += gelu_fast(acc[mf][nf][q] + bvs) * wv;
            }
#pragma unroll
        for (int mf = 0; mf < 4; ++mf)
#pragma unroll
            for (int q = 0; q < 4; ++q) {
                float vv = rs[mf][q];
                vv += __shfl_xor(vv, 1); vv += __shfl_xor(vv, 2);
                vv += __shfl_xor(vv, 4); vv += __shfl_xor(vv, 8);
                if (lr == 0) {
                    int m = chunk_off + row0 + wm * 64 + mf * 16 + lh * 4 + q;
                    partials[(size_t)(bx * 2 + wn) * 65536 + m] = vv;
                }
            }
    }
}

// ---------------------------------------------------------------------------
// f32 fallback GEMM for the small qa projection.
constexpr int BKF = 16;
__global__ __launch_bounds__(256)
void rowstats(const float* __restrict__ X, float2* __restrict__ st, int M)
{
    int wave = threadIdx.x >> 6, lane = threadIdx.x & 63;
    int row = blockIdx.x * 4 + wave;
    if (row >= M) return;
    const float4* xr = reinterpret_cast<const float4*>(X + (size_t)row * KDIM);
    float s = 0.f, ss = 0.f;
#pragma unroll
    for (int i = 0; i < 3; ++i) {
        float4 v = xr[lane + i * 64];
        s  += v.x + v.y + v.z + v.w;
        ss += v.x * v.x + v.y * v.y + v.z * v.z + v.w * v.w;
    }
    s = wave_sum(s); ss = wave_sum(ss);
    if (lane == 0) {
        float m = s * (1.0f / 768.0f);
        float var = ss * (1.0f / 768.0f) - m * m;
        float rstd = rsqrtf(var + 1e-5f);
        st[row] = make_float2(rstd, -m * rstd);
    }
}

template<int BM, int BN, int TM, int TN>
__global__ __launch_bounds__(256)
void gemm_fused(const float* __restrict__ X, const float2* __restrict__ st,
                const float* __restrict__ gw, const float* __restrict__ gb,
                const float* __restrict__ W, const float* __restrict__ bias,
                float* __restrict__ out, int M, int N)
{
    static_assert((BM / TM) * (BN / TN) == 256, "256 threads");
    __shared__ float As[BKF][BM];
    __shared__ float Bs[BKF][BN];
    const int t = threadIdx.x;
    constexpr int TXN = BN / TN;
    const int tx = t % TXN;
    const int ty = t / TXN;
    const int row0 = blockIdx.y * BM;
    const int col0 = blockIdx.x * BN;
    float acc[TM][TN] = {};
    constexpr int A_IT = BM * BKF / 4 / 256;
    constexpr int B_IT = BKF * BN / 4 / 256;
    for (int k0 = 0; k0 < KDIM; k0 += BKF) {
#pragma unroll
        for (int i = 0; i < A_IT; ++i) {
            int idx = t + i * 256;
            int r = idx >> 2;
            int c = (idx & 3) << 2;
            float4 xv = *reinterpret_cast<const float4*>(X + (size_t)(row0 + r) * KDIM + k0 + c);
            float2 s = st[row0 + r];
            float4 gv = *reinterpret_cast<const float4*>(gw + k0 + c);
            float4 bv = *reinterpret_cast<const float4*>(gb + k0 + c);
            As[c + 0][r] = fmaf(fmaf(xv.x, s.x, s.y), gv.x, bv.x);
            As[c + 1][r] = fmaf(fmaf(xv.y, s.x, s.y), gv.y, bv.y);
            As[c + 2][r] = fmaf(fmaf(xv.z, s.x, s.y), gv.z, bv.z);
            As[c + 3][r] = fmaf(fmaf(xv.w, s.x, s.y), gv.w, bv.w);
        }
#pragma unroll
        for (int i = 0; i < B_IT; ++i) {
            int idx = t + i * 256;
            int r = idx / (BN / 4);
            int c = (idx % (BN / 4)) << 2;
            *reinterpret_cast<float4*>(&Bs[r][c]) =
                *reinterpret_cast<const float4*>(W + (size_t)(k0 + r) * N + col0 + c);
        }
        __syncthreads();
#pragma unroll
        for (int kk = 0; kk < BKF; ++kk) {
            float a[TM], b[TN];
#pragma unroll
            for (int i = 0; i < TM; i += 4)
                *reinterpret_cast<float4*>(&a[i]) = *reinterpret_cast<const float4*>(&As[kk][ty * TM + i]);
#pragma unroll
            for (int j = 0; j < TN; j += 4)
                *reinterpret_cast<float4*>(&b[j]) = *reinterpret_cast<const float4*>(&Bs[kk][tx * TN + j]);
#pragma unroll
            for (int i = 0; i < TM; ++i)
#pragma unroll
                for (int j = 0; j < TN; ++j)
                    acc[i][j] = fmaf(a[i], b[j], acc[i][j]);
        }
        __syncthreads();
    }
#pragma unroll
    for (int i = 0; i < TM; ++i) {
        size_t row = row0 + ty * TM + i;
#pragma unroll
        for (int j = 0; j < TN; j += 4) {
            int col = col0 + tx * TN + j;
            float4 o;
            o.x = gelu_fast(acc[i][j + 0] + bias[col + 0]);
            o.y = gelu_fast(acc[i][j + 1] + bias[col + 1]);
            o.z = gelu_fast(acc[i][j + 2] + bias[col + 2]);
            o.w = gelu_fast(acc[i][j + 3] + bias[col + 3]);
            *reinterpret_cast<float4*>(out + row * N + col) = o;
        }
    }
}

// ---------------------------------------------------------------------------
// head: logits = sum(4 partials)+b2 -> softmax -> smooth -> softmax -> decode.
__global__ __launch_bounds__(64)
void head_kernel(const float* __restrict__ partials, const float* __restrict__ b2,
                 const float* __restrict__ sigma_p, float* __restrict__ out)
{
    int b = blockIdx.x, lane = threadIdx.x;
    __shared__ float ok[36];
    __shared__ float kg[32];
    __shared__ int sel[2];

    if (lane < 36) ok[lane] = 0.f;
    __syncthreads();

    float x = -3.4e38f;
    if (lane < 32) {
        int row = b * 32 + lane;
        x = b2[0];
#pragma unroll
        for (int p = 0; p < 4; ++p) x += partials[(size_t)p * 65536 + row];
    }
    float mx = wave_max(x);
    float e = (lane < 32) ? expf(x - mx) : 0.f;
    float sum = wave_sum(e);
    float ori = e / sum;
    if (lane < 32) {
        out[OFF_ORI + b * 32 + lane] = ori;
        ok[lane + 2] = ori;
    }
    __syncthreads();

    float sg = sigma_p[0];
    float kern[5]; float ks = 0.f;
#pragma unroll
    for (int k = 0; k < 5; ++k) { float xx = (float)(k - 2) / sg; kern[k] = expf(-0.5f * xx * xx); ks += kern[k]; }
    float sm = -3.4e38f;
    if (lane < 32) {
        sm = 0.f;
#pragma unroll
        for (int k = 0; k < 5; ++k) sm += (kern[k] / ks) * ok[lane + k];
    }
    float mx2 = wave_max(sm);
    float e2 = (lane < 32) ? expf(sm - mx2) : 0.f;
    float sum2 = wave_sum(e2);
    float kgv = e2 / sum2;
    if (lane < 32) {
        out[OFF_KG + b * 32 + lane] = kgv;
        kg[lane] = kgv;
    }
    __syncthreads();

    if (lane == 0) {
        int pm = 0; float bv = kg[0];
        for (int i = 1; i < 32; ++i) if (kg[i] > bv) { bv = kg[i]; pm = i; }
        float cum[33]; cum[0] = 0.f;
        for (int i = 0; i < 32; ++i) cum[i + 1] = cum[i] + kg[i];
        float bs = -3.4e38f; int bst = 0, ben = 0;
        const int wsz[3] = {1, 3, 5};
        for (int wi = 0; wi < 3; ++wi) {
            int w = wsz[wi];
            for (int s = 0; s + w <= 32; ++s) {
                if (pm >= s && pm < s + w) {
                    float sc = cum[s + w] - cum[s];
                    if (sc > bs) { bs = sc; bst = s; ben = s + w; }
                }
            }
        }
        out[OFF_MI + b * 2 + 0] = (float)bst;
        out[OFF_MI + b * 2 + 1] = (float)ben;
        out[OFF_ST + b] = (float)bst / 31.0f;
        out[OFF_ET + b] = (float)ben / 31.0f;
        sel[0] = bst; sel[1] = ben;
    }
    __syncthreads();
    if (lane < 32)
        out[OFF_MASK + b * 32 + lane] = (lane >= sel[0] && lane <= sel[1]) ? 1.0f : 0.0f;
}

// ---------------------------------------------------------------------------
extern "C" void kernel_launch(void* const* d_in, const int* in_sizes, int n_in,
                              void* d_out, int out_size, void* d_ws, size_t ws_size,
                              hipStream_t stream)
{
    const float* v      = (const float*)d_in[0];
    const float* qa     = (const float*)d_in[1];
    const float* vp_lng = (const float*)d_in[2];
    const float* vp_lnb = (const float*)d_in[3];
    const float* vp_w   = (const float*)d_in[4];
    const float* vp_b   = (const float*)d_in[5];
    const float* qp_lng = (const float*)d_in[6];
    const float* qp_lnb = (const float*)d_in[7];
    const float* qp_w   = (const float*)d_in[8];
    const float* qp_b   = (const float*)d_in[9];
    const float* g_lng  = (const float*)d_in[10];
    const float* g_lnb  = (const float*)d_in[11];
    const float* g_w1   = (const float*)d_in[12];
    const float* g_b1   = (const float*)d_in[13];
    const float* g_w2   = (const float*)d_in[14];
    const float* g_b2   = (const float*)d_in[15];
    const float* sigma  = (const float*)d_in[16];
    float* outf = (float*)d_out;

    // workspace layout (~213 MB)
    short* A1h = (short*)d_ws;                           // CHUNK*768
    short* A1l = A1h + (size_t)CHUNK * KDIM;
    uint32_t* vp_hl = (uint32_t*)(A1l + (size_t)CHUNK * KDIM);   // CHUNK*768 u32
    short* B1h = (short*)(vp_hl + (size_t)CHUNK * KDIM); // 768*768
    short* B1l = B1h + 768 * KDIM;
    short* B2h = B1l + 768 * KDIM;                       // 384*768
    short* B2l = B2h + 384 * KDIM;
    float* qa_p = (float*)(B2l + 384 * KDIM);            // 2048*768
    float* st_qa = qa_p + 2048 * KDIM;                   // 2048*2
    float* partials = st_qa + 4096;                      // 4*65536

    // qa path (small, f32 vector GEMM)
    rowstats<<<512, 256, 0, stream>>>(qa, (float2*)st_qa, 2048);
    gemm_fused<64, 64, 4, 4><<<dim3(12, 32), 256, 0, stream>>>(
        qa, (const float2*)st_qa, qp_lng, qp_lnb, qp_w, qp_b, qa_p, 2048, 768);

    // weight transpose + split
    prep_W<<<dim3(24, 24), 256, 0, stream>>>(vp_w, B1h, B1l, 768);
    prep_W<<<dim3(12, 24), 256, 0, stream>>>(g_w1, B2h, B2l, 384);

    constexpr int LDS8 = 81920;   // 2 bufs x 40 KB -> 2 blocks/CU

    for (int c = 0; c < 65536; c += CHUNK) {
        prep_A1<<<CHUNK / 4, 256, 0, stream>>>(v + (size_t)c * KDIM, vp_lng, vp_lnb, A1h, A1l);
        // v_p = gelu(A1 @ vp_w^T + vp_b): 128x192 tile, grid (4,256)=1024 blocks
        gemm8<0><<<dim3(4, CHUNK / 128), 256, LDS8, stream>>>(
            A1h, A1l, B1h, B1l, vp_b, vp_hl, nullptr, nullptr, 0);
        prep_A2<<<CHUNK / 4, 256, 0, stream>>>(vp_hl, qa_p, g_lng, g_lnb, A1h, A1l, c);
        // fused h@g_w1+gelu+dot(g_w2): 128x192 tile, grid (2,256)=512 blocks
        gemm8<1><<<dim3(2, CHUNK / 128), 256, LDS8, stream>>>(
            A1h, A1l, B2h, B2l, g_b1, nullptr, g_w2, partials, c);
    }

    head_kernel<<<2048, 64, 0, stream>>>(partials, g_b2, sigma, outf);
}

// Round 15
// 517.330 us; speedup vs baseline: 1.4452x; 1.0417x over previous
//
#include <hip/hip_runtime.h>
#include <math.h>
#include <stdint.h>

// ---------------------------------------------------------------------------
// GroundingModule — round 15: prep_A2 eliminated via LN2-affine commutation.
//   h = sa_r*(v_p @ (g2 (.) W1)) + ta_r*c1[n] + c2[n];  c1 = colsum(g2*W1),
//   c2 = b1 + lnb2@W1.  GEMM1 epilogue writes vph/vpl split AND per-row
//   partial stats (sum, sumsq, dot qa_p; qa slice cached in LDS);  stats2
//   (tiny) folds partials -> (sa,ta);  GEMM2 consumes vph/vpl raw with the
//   affine in its epilogue.  prep_A2's ~400MB HBM traffic -> ~13MB.
// GEMM core unchanged from r14: 2 blocks/CU, 256thr/4 waves, 128x192 tile,
// single-phase k-loop, counted vmcnt, slot-XOR swizzle, branchless gelu.
// ---------------------------------------------------------------------------

#define DEV __device__ __forceinline__

typedef __attribute__((ext_vector_type(8))) short short8v;   // 8 bf16
typedef __attribute__((ext_vector_type(4))) float f32x4;

constexpr int KDIM  = 768;
constexpr int CHUNK = 32768;

// output offsets (floats) in return order
constexpr int OFF_KG   = 0;
constexpr int OFF_MI   = 65536;
constexpr int OFF_ST   = 69632;
constexpr int OFF_ET   = 71680;
constexpr int OFF_MASK = 73728;
constexpr int OFF_ORI  = 139264;

DEV float wave_sum(float v) { for (int o = 32; o; o >>= 1) v += __shfl_xor(v, o); return v; }
DEV float wave_max(float v) { for (int o = 32; o; o >>= 1) v = fmaxf(v, __shfl_xor(v, o)); return v; }

// branchless gelu: 0.5x(1+erf(x/sqrt2)), erf via A&S 7.1.26 (|err|<=1.5e-7)
DEV float gelu_fast(float x) {
    float z = x * 0.70710678118654752f;
    float s = fabsf(z);
    float t = __builtin_amdgcn_rcpf(fmaf(0.3275911f, s, 1.0f));
    float p = t * fmaf(t, fmaf(t, fmaf(t, fmaf(t, 1.061405429f, -1.453152027f),
                                       1.421413741f), -0.284496736f), 0.254829592f);
    float e = __expf(-s * s);
    float er = copysignf(1.0f - p * e, z);
    return 0.5f * x * (1.0f + er);
}

DEV short f2bf(float x) {                       // f32 -> bf16 (RNE)
    uint32_t u = __builtin_bit_cast(uint32_t, x);
    u = u + 0x7fffu + ((u >> 16) & 1u);
    return (short)(u >> 16);
}
DEV float bf2f(short b) {
    uint32_t u = ((uint32_t)(uint16_t)b) << 16;
    return __builtin_bit_cast(float, u);
}
DEV float asf(uint32_t u) { return __builtin_bit_cast(float, u); }

DEV void gl_lds16(const void* g, void* l) {     // async 16B/lane global->LDS
    __builtin_amdgcn_global_load_lds(
        (const __attribute__((address_space(1))) uint32_t*)g,
        (__attribute__((address_space(3))) uint32_t*)l, 16, 0, 0);
}

// ---------------------------------------------------------------------------
// prep_A1: fused rowstats + LN-affine + hi/lo split.  One wave per row.
__global__ __launch_bounds__(256)
void prep_A1(const float* __restrict__ X, const float* __restrict__ g,
             const float* __restrict__ b, short* __restrict__ Ah, short* __restrict__ Al)
{
    int w = threadIdx.x >> 6, lane = threadIdx.x & 63;
    int row = blockIdx.x * 4 + w;
    const float4* xr = (const float4*)(X + (size_t)row * KDIM);
    float4 xv[3]; float s = 0.f, ss = 0.f;
#pragma unroll
    for (int i = 0; i < 3; ++i) {
        xv[i] = xr[lane + i * 64];
        s  += xv[i].x + xv[i].y + xv[i].z + xv[i].w;
        ss += xv[i].x * xv[i].x + xv[i].y * xv[i].y + xv[i].z * xv[i].z + xv[i].w * xv[i].w;
    }
    s = wave_sum(s); ss = wave_sum(ss);
    float m = s * (1.f / 768.f), var = ss * (1.f / 768.f) - m * m;
    float sa = rsqrtf(var + 1e-5f), ta = -m * sa;
#pragma unroll
    for (int i = 0; i < 3; ++i) {
        int idx = lane + i * 64;
        float4 gv = ((const float4*)g)[idx];
        float4 bv = ((const float4*)b)[idx];
        float a0 = fmaf(fmaf(xv[i].x, sa, ta), gv.x, bv.x);
        float a1 = fmaf(fmaf(xv[i].y, sa, ta), gv.y, bv.y);
        float a2 = fmaf(fmaf(xv[i].z, sa, ta), gv.z, bv.z);
        float a3 = fmaf(fmaf(xv[i].w, sa, ta), gv.w, bv.w);
        short h0 = f2bf(a0), h1 = f2bf(a1), h2 = f2bf(a2), h3 = f2bf(a3);
        ushort4 hv, lv;
        hv.x = (uint16_t)h0; hv.y = (uint16_t)h1; hv.z = (uint16_t)h2; hv.w = (uint16_t)h3;
        lv.x = (uint16_t)f2bf(a0 - bf2f(h0)); lv.y = (uint16_t)f2bf(a1 - bf2f(h1));
        lv.z = (uint16_t)f2bf(a2 - bf2f(h2)); lv.w = (uint16_t)f2bf(a3 - bf2f(h3));
        ((ushort4*)(Ah + (size_t)row * KDIM))[idx] = hv;
        ((ushort4*)(Al + (size_t)row * KDIM))[idx] = lv;
    }
}

// ---------------------------------------------------------------------------
// prep_W: transpose + hi/lo split, optional per-k scale.
// W[k][n] f32 -> Bh/Bl[n][k] bf16 of (scale[k]*W[k][n]).
__global__ __launch_bounds__(256)
void prep_W(const float* __restrict__ W, const float* __restrict__ scale,
            short* __restrict__ Bh, short* __restrict__ Bl, int N)
{
    __shared__ float t[32][33];
    int bx = blockIdx.x, by = blockIdx.y;
    int lx = threadIdx.x & 31, ly = threadIdx.x >> 5;
#pragma unroll
    for (int r = 0; r < 32; r += 8)
        t[ly + r][lx] = W[(size_t)(by * 32 + ly + r) * N + bx * 32 + lx];
    __syncthreads();
    float sc = scale ? scale[by * 32 + lx] : 1.0f;
#pragma unroll
    for (int r = 0; r < 32; r += 8) {
        float v = t[lx][ly + r] * sc;              // k = by*32+lx
        short hi = f2bf(v);
        size_t o = (size_t)(bx * 32 + ly + r) * KDIM + by * 32 + lx;
        Bh[o] = hi;
        Bl[o] = f2bf(v - bf2f(hi));
    }
}

// ---------------------------------------------------------------------------
// colsums: c1[n] = sum_k g2[k]*W1[k][n];  c2[n] = b1[n] + sum_k lnb2[k]*W1[k][n]
__global__ __launch_bounds__(256)
void colsums(const float* __restrict__ W1, const float* __restrict__ g2,
             const float* __restrict__ lb2, const float* __restrict__ b1,
             float* __restrict__ c1, float* __restrict__ c2)
{
    int w = threadIdx.x >> 6, lane = threadIdx.x & 63;
    int n = blockIdx.x * 4 + w;                 // 0..383
    float s1 = 0.f, s2 = 0.f;
    for (int k = lane; k < 768; k += 64) {
        float wv = W1[(size_t)k * 384 + n];
        s1 += g2[k] * wv;
        s2 += lb2[k] * wv;
    }
    s1 = wave_sum(s1); s2 = wave_sum(s2);
    if (lane == 0) { c1[n] = s1; c2[n] = b1[n] + s2; }
}

// ---------------------------------------------------------------------------
// stats2: fold 8 column-partials per row -> (sa, ta) for the LN2+gate affine.
__global__ __launch_bounds__(256)
void stats2(const float* __restrict__ sums, float2* __restrict__ st2, int chunk_off)
{
    int r = chunk_off + blockIdx.x * 256 + threadIdx.x;
    float s = 0.f, ss = 0.f, d = 0.f;
#pragma unroll
    for (int p = 0; p < 8; ++p) {
        s  += sums[(size_t)(0 * 8 + p) * 65536 + r];
        ss += sums[(size_t)(1 * 8 + p) * 65536 + r];
        d  += sums[(size_t)(2 * 8 + p) * 65536 + r];
    }
    float gate = tanhf(d);
    float m = s * (1.f / 768.f), var = ss * (1.f / 768.f) - m * m;
    float den = rsqrtf(gate * gate * var + 1e-5f);
    st2[r] = make_float2(gate * den, -gate * m * den);
}

// ---------------------------------------------------------------------------
// Split-bf16 MFMA GEMM, 2 blocks/CU.  256 thr / 4 waves (2x2), BM=128 BN=192,
// BK=32.  Single-phase k-loop; LDS buf 40KB x2.
//   MODE 0: gelu epilogue -> vph/vpl split + row-partial stats (sum,sq,dot qa).
//   MODE 1: affine epilogue h=gelu(sa*acc+ta*c1+c2), row-dot w2 -> partials.
#define VMW(N_) asm volatile("s_waitcnt vmcnt(" #N_ ")" ::: "memory")
#define SCB __builtin_amdgcn_sched_barrier(0)

#define STG(G_, KT_) gl_lds16(sp[G_] + (KT_) * 32,                            \
    lds + (((KT_) & 1) ? BUFSZ : 0) + (G_) * 4096 + toff)

#define STGA10(KT_) do { STG(0, KT_); STG(1, KT_); STG(2, KT_); STG(3, KT_);  \
    STG(4, KT_); STG(5, KT_); STG(6, KT_); STG(7, KT_); STG(8, KT_);          \
    STG(9, KT_); } while (0)

#define RDA(dst, BOFF) do { _Pragma("unroll")                                 \
    for (int mf = 0; mf < 4; ++mf) {                                          \
        int rA = wm * 64 + mf * 16 + lr;                                      \
        dst[mf] = *(const short8v*)(bb + (BOFF) + rA * 64 +                   \
                                    ((lh ^ ((rA >> 1) & 3)) << 4));           \
    } } while (0)

#define RDB(dst, BOFF) do { _Pragma("unroll")                                 \
    for (int nf = 0; nf < 6; ++nf) {                                          \
        int rB = wn * 96 + nf * 16 + lr;                                      \
        dst[nf] = *(const short8v*)(bb + (BOFF) + rB * 64 +                   \
                                    ((lh ^ ((rB >> 1) & 3)) << 4));           \
    } } while (0)

#define BODY(KT_, NL_) do {                                                   \
    if (NL_) { STGA10((KT_) + 1); }                                           \
    SCB;                                                                      \
    if (NL_) { VMW(10); } else { VMW(0); }                                    \
    SCB;                                                                      \
    __builtin_amdgcn_s_barrier();            /* buf[KT_] staged for all */    \
    const char* bb = lds + (((KT_) & 1) ? BUFSZ : 0);                         \
    RDA(ah, 0); RDA(al, 8192); RDB(bh, 16384); RDB(bl, 28672);                \
    asm volatile("s_waitcnt lgkmcnt(0)" ::: "memory");                        \
    SCB;                                                                      \
    __builtin_amdgcn_s_barrier();            /* reads done for all */         \
    __builtin_amdgcn_s_setprio(1);                                            \
    _Pragma("unroll")                                                         \
    for (int mf = 0; mf < 4; ++mf)                                            \
        _Pragma("unroll")                                                     \
        for (int nf = 0; nf < 6; ++nf) {                                      \
            acc[mf][nf] = __builtin_amdgcn_mfma_f32_16x16x32_bf16(            \
                ah[mf], bh[nf], acc[mf][nf], 0, 0, 0);                        \
            acc[mf][nf] = __builtin_amdgcn_mfma_f32_16x16x32_bf16(            \
                ah[mf], bl[nf], acc[mf][nf], 0, 0, 0);                        \
            acc[mf][nf] = __builtin_amdgcn_mfma_f32_16x16x32_bf16(            \
                al[mf], bh[nf], acc[mf][nf], 0, 0, 0);                        \
        }                                                                     \
    __builtin_amdgcn_s_setprio(0);                                            \
    SCB;                                                                      \
} while (0)

template<int MODE>
__global__ __launch_bounds__(256, 2)
void gemm8(const short* __restrict__ Ah_g, const short* __restrict__ Al_g,
           const short* __restrict__ Bh_g, const short* __restrict__ Bl_g,
           const float* __restrict__ bias,
           short* __restrict__ Oh, short* __restrict__ Ol,
           const float* __restrict__ qa_p, float* __restrict__ sums,
           const float2* __restrict__ st2, const float* __restrict__ c1,
           const float* __restrict__ c2, const float* __restrict__ w2,
           float* __restrict__ partials, int chunk_off)
{
    constexpr int BUFSZ = 40960;              // 40 KB per buffer
    extern __shared__ __align__(16) char lds[];

    const int t = threadIdx.x;
    const int w = t >> 6, lane = t & 63;
    const int lr = lane & 15, lh = lane >> 4;
    const int wm = w >> 1, wn = w & 1;        // 2 x 2 wave grid

    const int gx = gridDim.x, nwg = gx * gridDim.y;
    int bidx = blockIdx.y * gx + blockIdx.x;
    int wid = (bidx & 7) * (nwg >> 3) + (bidx >> 3);
    const int bx = wid % gx, by = wid / gx;
    const int row0 = by * 128, col0 = bx * 192;

    // stage source pointers (k=0); units Ah0,Ah1,Al0,Al1,Bh0..2,Bl0..2.
    const int r_ = t >> 2, c_ = t & 3;
    const int swz_ = (c_ ^ ((r_ >> 1) & 3)) << 3;
    const int toff = t * 16;
    const short* sp[10];
    sp[0] = Ah_g + (size_t)(row0 + r_)       * KDIM + swz_;
    sp[1] = Ah_g + (size_t)(row0 + 64 + r_)  * KDIM + swz_;
    sp[2] = Al_g + (size_t)(row0 + r_)       * KDIM + swz_;
    sp[3] = Al_g + (size_t)(row0 + 64 + r_)  * KDIM + swz_;
    sp[4] = Bh_g + (size_t)(col0 + r_)       * KDIM + swz_;
    sp[5] = Bh_g + (size_t)(col0 + 64 + r_)  * KDIM + swz_;
    sp[6] = Bh_g + (size_t)(col0 + 128 + r_) * KDIM + swz_;
    sp[7] = Bl_g + (size_t)(col0 + r_)       * KDIM + swz_;
    sp[8] = Bl_g + (size_t)(col0 + 64 + r_)  * KDIM + swz_;
    sp[9] = Bl_g + (size_t)(col0 + 128 + r_) * KDIM + swz_;

    f32x4 acc[4][6] = {};
    short8v ah[4], al[4], bh[6], bl[6];

    STGA10(0);
    SCB;

    for (int kt = 0; kt < 24; kt += 2) {
        BODY(kt,     true);
        BODY(kt + 1, (kt + 1 < 23));
    }

    if (MODE == 0) {
        // cache qa_p slice for this block: 4 batch rows x 192 cols.
        __syncthreads();
        float* qal = (float*)lds;
        int bbase = (chunk_off >> 5) + (row0 >> 5);
        for (int j = t; j < 768; j += 256)
            qal[j] = qa_p[(size_t)(bbase + j / 192) * 768 + col0 + (j % 192)];
        __syncthreads();
#pragma unroll
        for (int mf = 0; mf < 4; ++mf) {
            const int bp = wm * 2 + (mf >> 1);
#pragma unroll
            for (int q = 0; q < 4; ++q) {
                int m = row0 + wm * 64 + mf * 16 + lh * 4 + q;
                float s = 0.f, ssq = 0.f, d = 0.f;
#pragma unroll
                for (int nf = 0; nf < 6; ++nf) {
                    int ncol = wn * 96 + nf * 16 + lr;
                    int n = col0 + ncol;
                    float gv = gelu_fast(acc[mf][nf][q] + bias[n]);
                    uint32_t u  = __builtin_bit_cast(uint32_t, gv);
                    uint32_t hb = u & 0xffff0000u;
                    float rem   = gv - asf(hb);
                    Oh[(size_t)m * 768 + n] = (short)(hb >> 16);
                    Ol[(size_t)m * 768 + n] = f2bf(rem);
                    s += gv; ssq += gv * gv; d += gv * qal[bp * 192 + ncol];
                }
                for (int o = 1; o < 16; o <<= 1) {
                    s += __shfl_xor(s, o); ssq += __shfl_xor(ssq, o); d += __shfl_xor(d, o);
                }
                if (lr == 0) {
                    int gr = chunk_off + m;
                    int pc = bx * 2 + wn;
                    sums[(size_t)(0 * 8 + pc) * 65536 + gr] = s;
                    sums[(size_t)(1 * 8 + pc) * 65536 + gr] = ssq;
                    sums[(size_t)(2 * 8 + pc) * 65536 + gr] = d;
                }
            }
        }
    } else {
        float c1v[6], c2v[6], wv[6];
#pragma unroll
        for (int nf = 0; nf < 6; ++nf) {
            int n = col0 + wn * 96 + nf * 16 + lr;
            c1v[nf] = c1[n]; c2v[nf] = c2[n]; wv[nf] = w2[n];
        }
        float rs[4][4] = {};
#pragma unroll
        for (int mf = 0; mf < 4; ++mf)
#pragma unroll
            for (int q = 0; q < 4; ++q) {
                int gm = chunk_off + row0 + wm * 64 + mf * 16 + lh * 4 + q;
                float2 st = st2[gm];
#pragma unroll
                for (int nf = 0; nf < 6; ++nf) {
                    float h = fmaf(st.x, acc[mf][nf][q], fmaf(st.y, c1v[nf], c2v[nf]));
                    rs[mf][q] += gelu_fast(h) * wv[nf];
                }
            }
#pragma unroll
        for (int mf = 0; mf < 4; ++mf)
#pragma unroll
            for (int q = 0; q < 4; ++q) {
                float vv = rs[mf][q];
                vv += __shfl_xor(vv, 1); vv += __shfl_xor(vv, 2);
                vv += __shfl_xor(vv, 4); vv += __shfl_xor(vv, 8);
                if (lr == 0) {
                    int gm = chunk_off + row0 + wm * 64 + mf * 16 + lh * 4 + q;
                    partials[(size_t)(bx * 2 + wn) * 65536 + gm] = vv;
                }
            }
    }
}

// ---------------------------------------------------------------------------
// f32 fallback GEMM for the small qa projection.
constexpr int BKF = 16;
__global__ __launch_bounds__(256)
void rowstats(const float* __restrict__ X, float2* __restrict__ st, int M)
{
    int wave = threadIdx.x >> 6, lane = threadIdx.x & 63;
    int row = blockIdx.x * 4 + wave;
    if (row >= M) return;
    const float4* xr = reinterpret_cast<const float4*>(X + (size_t)row * KDIM);
    float s = 0.f, ss = 0.f;
#pragma unroll
    for (int i = 0; i < 3; ++i) {
        float4 v = xr[lane + i * 64];
        s  += v.x + v.y + v.z + v.w;
        ss += v.x * v.x + v.y * v.y + v.z * v.z + v.w * v.w;
    }
    s = wave_sum(s); ss = wave_sum(ss);
    if (lane == 0) {
        float m = s * (1.0f / 768.0f);
        float var = ss * (1.0f / 768.0f) - m * m;
        float rstd = rsqrtf(var + 1e-5f);
        st[row] = make_float2(rstd, -m * rstd);
    }
}

template<int BM, int BN, int TM, int TN>
__global__ __launch_bounds__(256)
void gemm_fused(const float* __restrict__ X, const float2* __restrict__ st,
                const float* __restrict__ gw, const float* __restrict__ gb,
                const float* __restrict__ W, const float* __restrict__ bias,
                float* __restrict__ out, int M, int N)
{
    static_assert((BM / TM) * (BN / TN) == 256, "256 threads");
    __shared__ float As[BKF][BM];
    __shared__ float Bs[BKF][BN];
    const int t = threadIdx.x;
    constexpr int TXN = BN / TN;
    const int tx = t % TXN;
    const int ty = t / TXN;
    const int row0 = blockIdx.y * BM;
    const int col0 = blockIdx.x * BN;
    float acc[TM][TN] = {};
    constexpr int A_IT = BM * BKF / 4 / 256;
    constexpr int B_IT = BKF * BN / 4 / 256;
    for (int k0 = 0; k0 < KDIM; k0 += BKF) {
#pragma unroll
        for (int i = 0; i < A_IT; ++i) {
            int idx = t + i * 256;
            int r = idx >> 2;
            int c = (idx & 3) << 2;
            float4 xv = *reinterpret_cast<const float4*>(X + (size_t)(row0 + r) * KDIM + k0 + c);
            float2 s = st[row0 + r];
            float4 gv = *reinterpret_cast<const float4*>(gw + k0 + c);
            float4 bv = *reinterpret_cast<const float4*>(gb + k0 + c);
            As[c + 0][r] = fmaf(fmaf(xv.x, s.x, s.y), gv.x, bv.x);
            As[c + 1][r] = fmaf(fmaf(xv.y, s.x, s.y), gv.y, bv.y);
            As[c + 2][r] = fmaf(fmaf(xv.z, s.x, s.y), gv.z, bv.z);
            As[c + 3][r] = fmaf(fmaf(xv.w, s.x, s.y), gv.w, bv.w);
        }
#pragma unroll
        for (int i = 0; i < B_IT; ++i) {
            int idx = t + i * 256;
            int r = idx / (BN / 4);
            int c = (idx % (BN / 4)) << 2;
            *reinterpret_cast<float4*>(&Bs[r][c]) =
                *reinterpret_cast<const float4*>(W + (size_t)(k0 + r) * N + col0 + c);
        }
        __syncthreads();
#pragma unroll
        for (int kk = 0; kk < BKF; ++kk) {
            float a[TM], b[TN];
#pragma unroll
            for (int i = 0; i < TM; i += 4)
                *reinterpret_cast<float4*>(&a[i]) = *reinterpret_cast<const float4*>(&As[kk][ty * TM + i]);
#pragma unroll
            for (int j = 0; j < TN; j += 4)
                *reinterpret_cast<float4*>(&b[j]) = *reinterpret_cast<const float4*>(&Bs[kk][tx * TN + j]);
#pragma unroll
            for (int i = 0; i < TM; ++i)
#pragma unroll
                for (int j = 0; j < TN; ++j)
                    acc[i][j] = fmaf(a[i], b[j], acc[i][j]);
        }
        __syncthreads();
    }
#pragma unroll
    for (int i = 0; i < TM; ++i) {
        size_t row = row0 + ty * TM + i;
#pragma unroll
        for (int j = 0; j < TN; j += 4) {
            int col = col0 + tx * TN + j;
            float4 o;
            o.x = gelu_fast(acc[i][j + 0] + bias[col + 0]);
            o.y = gelu_fast(acc[i][j + 1] + bias[col + 1]);
            o.z = gelu_fast(acc[i][j + 2] + bias[col + 2]);
            o.w = gelu_fast(acc[i][j + 3] + bias[col + 3]);
            *reinterpret_cast<float4*>(out + row * N + col) = o;
        }
    }
}

// ---------------------------------------------------------------------------
// head: logits = sum(4 partials)+b2 -> softmax -> smooth -> softmax -> decode.
__global__ __launch_bounds__(64)
void head_kernel(const float* __restrict__ partials, const float* __restrict__ b2,
                 const float* __restrict__ sigma_p, float* __restrict__ out)
{
    int b = blockIdx.x, lane = threadIdx.x;
    __shared__ float ok[36];
    __shared__ float kg[32];
    __shared__ int sel[2];

    if (lane < 36) ok[lane] = 0.f;
    __syncthreads();

    float x = -3.4e38f;
    if (lane < 32) {
        int row = b * 32 + lane;
        x = b2[0];
#pragma unroll
        for (int p = 0; p < 4; ++p) x += partials[(size_t)p * 65536 + row];
    }
    float mx = wave_max(x);
    float e = (lane < 32) ? expf(x - mx) : 0.f;
    float sum = wave_sum(e);
    float ori = e / sum;
    if (lane < 32) {
        out[OFF_ORI + b * 32 + lane] = ori;
        ok[lane + 2] = ori;
    }
    __syncthreads();

    float sg = sigma_p[0];
    float kern[5]; float ks = 0.f;
#pragma unroll
    for (int k = 0; k < 5; ++k) { float xx = (float)(k - 2) / sg; kern[k] = expf(-0.5f * xx * xx); ks += kern[k]; }
    float sm = -3.4e38f;
    if (lane < 32) {
        sm = 0.f;
#pragma unroll
        for (int k = 0; k < 5; ++k) sm += (kern[k] / ks) * ok[lane + k];
    }
    float mx2 = wave_max(sm);
    float e2 = (lane < 32) ? expf(sm - mx2) : 0.f;
    float sum2 = wave_sum(e2);
    float kgv = e2 / sum2;
    if (lane < 32) {
        out[OFF_KG + b * 32 + lane] = kgv;
        kg[lane] = kgv;
    }
    __syncthreads();

    if (lane == 0) {
        int pm = 0; float bv = kg[0];
        for (int i = 1; i < 32; ++i) if (kg[i] > bv) { bv = kg[i]; pm = i; }
        float cum[33]; cum[0] = 0.f;
        for (int i = 0; i < 32; ++i) cum[i + 1] = cum[i] + kg[i];
        float bs = -3.4e38f; int bst = 0, ben = 0;
        const int wsz[3] = {1, 3, 5};
        for (int wi = 0; wi < 3; ++wi) {
            int w = wsz[wi];
            for (int s = 0; s + w <= 32; ++s) {
                if (pm >= s && pm < s + w) {
                    float sc = cum[s + w] - cum[s];
                    if (sc > bs) { bs = sc; bst = s; ben = s + w; }
                }
            }
        }
        out[OFF_MI + b * 2 + 0] = (float)bst;
        out[OFF_MI + b * 2 + 1] = (float)ben;
        out[OFF_ST + b] = (float)bst / 31.0f;
        out[OFF_ET + b] = (float)ben / 31.0f;
        sel[0] = bst; sel[1] = ben;
    }
    __syncthreads();
    if (lane < 32)
        out[OFF_MASK + b * 32 + lane] = (lane >= sel[0] && lane <= sel[1]) ? 1.0f : 0.0f;
}

// ---------------------------------------------------------------------------
extern "C" void kernel_launch(void* const* d_in, const int* in_sizes, int n_in,
                              void* d_out, int out_size, void* d_ws, size_t ws_size,
                              hipStream_t stream)
{
    const float* v      = (const float*)d_in[0];
    const float* qa     = (const float*)d_in[1];
    const float* vp_lng = (const float*)d_in[2];
    const float* vp_lnb = (const float*)d_in[3];
    const float* vp_w   = (const float*)d_in[4];
    const float* vp_b   = (const float*)d_in[5];
    const float* qp_lng = (const float*)d_in[6];
    const float* qp_lnb = (const float*)d_in[7];
    const float* qp_w   = (const float*)d_in[8];
    const float* qp_b   = (const float*)d_in[9];
    const float* g_lng  = (const float*)d_in[10];
    const float* g_lnb  = (const float*)d_in[11];
    const float* g_w1   = (const float*)d_in[12];
    const float* g_b1   = (const float*)d_in[13];
    const float* g_w2   = (const float*)d_in[14];
    const float* g_b2   = (const float*)d_in[15];
    const float* sigma  = (const float*)d_in[16];
    float* outf = (float*)d_out;

    // workspace layout (~220 MB)
    short* A1h = (short*)d_ws;                           // CHUNK*768
    short* A1l = A1h + (size_t)CHUNK * KDIM;
    short* vph = A1l + (size_t)CHUNK * KDIM;             // CHUNK*768
    short* vpl = vph + (size_t)CHUNK * KDIM;
    short* B1h = vpl + (size_t)CHUNK * KDIM;             // 768*768
    short* B1l = B1h + 768 * KDIM;
    short* B2h = B1l + 768 * KDIM;                       // 384*768
    short* B2l = B2h + 384 * KDIM;
    float* qa_p = (float*)(B2l + 384 * KDIM);            // 2048*768
    float* st_qa = qa_p + 2048 * KDIM;                   // 2048*2
    float* partials = st_qa + 4096;                      // 4*65536
    float* sums = partials + 4 * 65536;                  // 3*8*65536
    float2* st2 = (float2*)(sums + 24 * 65536);          // 65536
    float* c1 = (float*)(st2 + 65536);                   // 384
    float* c2 = c1 + 384;                                // 384

    // qa path (small, f32 vector GEMM)
    rowstats<<<512, 256, 0, stream>>>(qa, (float2*)st_qa, 2048);
    gemm_fused<64, 64, 4, 4><<<dim3(12, 32), 256, 0, stream>>>(
        qa, (const float2*)st_qa, qp_lng, qp_lnb, qp_w, qp_b, qa_p, 2048, 768);

    // weight prep: B1 = split(vp_w); B2 = split(g_lng (.) g_w1); colsums c1/c2
    prep_W<<<dim3(24, 24), 256, 0, stream>>>(vp_w, nullptr, B1h, B1l, 768);
    prep_W<<<dim3(12, 24), 256, 0, stream>>>(g_w1, g_lng, B2h, B2l, 384);
    colsums<<<96, 256, 0, stream>>>(g_w1, g_lng, g_lnb, g_b1, c1, c2);

    constexpr int LDS8 = 81920;   // 2 bufs x 40 KB -> 2 blocks/CU

    for (int c = 0; c < 65536; c += CHUNK) {
        prep_A1<<<CHUNK / 4, 256, 0, stream>>>(v + (size_t)c * KDIM, vp_lng, vp_lnb, A1h, A1l);
        // v_p = gelu(A1 @ vp_w^T + vp_b) -> vph/vpl + row stats partials
        gemm8<0><<<dim3(4, CHUNK / 128), 256, LDS8, stream>>>(
            A1h, A1l, B1h, B1l, vp_b, vph, vpl, qa_p, sums,
            nullptr, nullptr, nullptr, nullptr, nullptr, c);
        stats2<<<CHUNK / 256, 256, 0, stream>>>(sums, st2, c);
        // h = gelu(sa*(vp @ g2W1) + ta*c1 + c2); fused dot(g_w2) -> partials
        gemm8<1><<<dim3(2, CHUNK / 128), 256, LDS8, stream>>>(
            vph, vpl, B2h, B2l, nullptr, nullptr, nullptr, nullptr, nullptr,
            (const float2*)st2, c1, c2, g_w2, partials, c);
    }

    head_kernel<<<2048, 64, 0, stream>>>(partials, g_b2, sigma, outf);
}

// Round 16
// 516.014 us; speedup vs baseline: 1.4489x; 1.0026x over previous
//
#include <hip/hip_runtime.h>
#include <math.h>
#include <stdint.h>

// ---------------------------------------------------------------------------
// GroundingModule — round 16: packed-u32 hi/lo operand format end-to-end.
//   A operands stored as u32 (hi-bf16 <<16 | lo-bf16): prep_A1 + MODE0
//   epilogue write ONE u32/element (r15 wrote two scattered 2B stores - the
//   regression); gemm8 stages packed 128B rows and unpacks ah/al in regs
//   (2x ds_read_b128 + 16 shift/or per fragment pair).
// Keeps r15's prep_A2 elimination (LN2-affine commutation, stats in MODE0
// epilogue, stats2 fold, affine MODE1 epilogue) and the r14 schedule:
// 2 blocks/CU, 256thr/4 waves, 128x192, single-phase k-loop, VMW(10).
// ---------------------------------------------------------------------------

#define DEV __device__ __forceinline__

typedef __attribute__((ext_vector_type(8))) short short8v;   // 8 bf16
typedef __attribute__((ext_vector_type(4))) float f32x4;
typedef __attribute__((ext_vector_type(4))) uint32_t u32x4;

constexpr int KDIM  = 768;
constexpr int CHUNK = 32768;

// output offsets (floats) in return order
constexpr int OFF_KG   = 0;
constexpr int OFF_MI   = 65536;
constexpr int OFF_ST   = 69632;
constexpr int OFF_ET   = 71680;
constexpr int OFF_MASK = 73728;
constexpr int OFF_ORI  = 139264;

DEV float wave_sum(float v) { for (int o = 32; o; o >>= 1) v += __shfl_xor(v, o); return v; }
DEV float wave_max(float v) { for (int o = 32; o; o >>= 1) v = fmaxf(v, __shfl_xor(v, o)); return v; }

// branchless gelu: 0.5x(1+erf(x/sqrt2)), erf via A&S 7.1.26 (|err|<=1.5e-7)
DEV float gelu_fast(float x) {
    float z = x * 0.70710678118654752f;
    float s = fabsf(z);
    float t = __builtin_amdgcn_rcpf(fmaf(0.3275911f, s, 1.0f));
    float p = t * fmaf(t, fmaf(t, fmaf(t, fmaf(t, 1.061405429f, -1.453152027f),
                                       1.421413741f), -0.284496736f), 0.254829592f);
    float e = __expf(-s * s);
    float er = copysignf(1.0f - p * e, z);
    return 0.5f * x * (1.0f + er);
}

DEV short f2bf(float x) {                       // f32 -> bf16 (RNE)
    uint32_t u = __builtin_bit_cast(uint32_t, x);
    u = u + 0x7fffu + ((u >> 16) & 1u);
    return (short)(u >> 16);
}
DEV float bf2f(short b) {
    uint32_t u = ((uint32_t)(uint16_t)b) << 16;
    return __builtin_bit_cast(float, u);
}
DEV float asf(uint32_t u) { return __builtin_bit_cast(float, u); }

// pack f32 -> u32 (truncated-hi bits in TOP, RNE lo-bf16 of remainder in LOW)
DEV uint32_t packhl(float x) {
    uint32_t u  = __builtin_bit_cast(uint32_t, x);
    uint32_t hb = u & 0xffff0000u;
    float rem   = x - asf(hb);
    return hb | (uint32_t)(uint16_t)f2bf(rem);
}

DEV void gl_lds16(const void* g, void* l) {     // async 16B/lane global->LDS
    __builtin_amdgcn_global_load_lds(
        (const __attribute__((address_space(1))) uint32_t*)g,
        (__attribute__((address_space(3))) uint32_t*)l, 16, 0, 0);
}

// unpack 8 packed u32 -> hi short8v + lo short8v
DEV void unpack8(u32x4 p0, u32x4 p1, short8v& hi, short8v& lo) {
    u32x4 h, l;
    h.x = (p0.x >> 16) | (p0.y & 0xffff0000u);
    h.y = (p0.z >> 16) | (p0.w & 0xffff0000u);
    h.z = (p1.x >> 16) | (p1.y & 0xffff0000u);
    h.w = (p1.z >> 16) | (p1.w & 0xffff0000u);
    l.x = (p0.x & 0xffffu) | (p0.y << 16);
    l.y = (p0.z & 0xffffu) | (p0.w << 16);
    l.z = (p1.x & 0xffffu) | (p1.y << 16);
    l.w = (p1.z & 0xffffu) | (p1.w << 16);
    hi = __builtin_bit_cast(short8v, h);
    lo = __builtin_bit_cast(short8v, l);
}

// ---------------------------------------------------------------------------
// prep_A1: fused rowstats + LN-affine + packed hi/lo u32.  One wave per row.
__global__ __launch_bounds__(256)
void prep_A1(const float* __restrict__ X, const float* __restrict__ g,
             const float* __restrict__ b, uint32_t* __restrict__ Ap)
{
    int w = threadIdx.x >> 6, lane = threadIdx.x & 63;
    int row = blockIdx.x * 4 + w;
    const float4* xr = (const float4*)(X + (size_t)row * KDIM);
    float4 xv[3]; float s = 0.f, ss = 0.f;
#pragma unroll
    for (int i = 0; i < 3; ++i) {
        xv[i] = xr[lane + i * 64];
        s  += xv[i].x + xv[i].y + xv[i].z + xv[i].w;
        ss += xv[i].x * xv[i].x + xv[i].y * xv[i].y + xv[i].z * xv[i].z + xv[i].w * xv[i].w;
    }
    s = wave_sum(s); ss = wave_sum(ss);
    float m = s * (1.f / 768.f), var = ss * (1.f / 768.f) - m * m;
    float sa = rsqrtf(var + 1e-5f), ta = -m * sa;
#pragma unroll
    for (int i = 0; i < 3; ++i) {
        int idx = lane + i * 64;
        float4 gv = ((const float4*)g)[idx];
        float4 bv = ((const float4*)b)[idx];
        uint4 ov;
        ov.x = packhl(fmaf(fmaf(xv[i].x, sa, ta), gv.x, bv.x));
        ov.y = packhl(fmaf(fmaf(xv[i].y, sa, ta), gv.y, bv.y));
        ov.z = packhl(fmaf(fmaf(xv[i].z, sa, ta), gv.z, bv.z));
        ov.w = packhl(fmaf(fmaf(xv[i].w, sa, ta), gv.w, bv.w));
        ((uint4*)(Ap + (size_t)row * KDIM))[idx] = ov;
    }
}

// ---------------------------------------------------------------------------
// prep_W: transpose + hi/lo split, optional per-k scale.
// W[k][n] f32 -> Bh/Bl[n][k] bf16 of (scale[k]*W[k][n]).
__global__ __launch_bounds__(256)
void prep_W(const float* __restrict__ W, const float* __restrict__ scale,
            short* __restrict__ Bh, short* __restrict__ Bl, int N)
{
    __shared__ float t[32][33];
    int bx = blockIdx.x, by = blockIdx.y;
    int lx = threadIdx.x & 31, ly = threadIdx.x >> 5;
#pragma unroll
    for (int r = 0; r < 32; r += 8)
        t[ly + r][lx] = W[(size_t)(by * 32 + ly + r) * N + bx * 32 + lx];
    __syncthreads();
    float sc = scale ? scale[by * 32 + lx] : 1.0f;
#pragma unroll
    for (int r = 0; r < 32; r += 8) {
        float v = t[lx][ly + r] * sc;              // k = by*32+lx
        short hi = f2bf(v);
        size_t o = (size_t)(bx * 32 + ly + r) * KDIM + by * 32 + lx;
        Bh[o] = hi;
        Bl[o] = f2bf(v - bf2f(hi));
    }
}

// ---------------------------------------------------------------------------
// colsums: c1[n] = sum_k g2[k]*W1[k][n];  c2[n] = b1[n] + sum_k lnb2[k]*W1[k][n]
__global__ __launch_bounds__(256)
void colsums(const float* __restrict__ W1, const float* __restrict__ g2,
             const float* __restrict__ lb2, const float* __restrict__ b1,
             float* __restrict__ c1, float* __restrict__ c2)
{
    int w = threadIdx.x >> 6, lane = threadIdx.x & 63;
    int n = blockIdx.x * 4 + w;                 // 0..383
    float s1 = 0.f, s2 = 0.f;
    for (int k = lane; k < 768; k += 64) {
        float wv = W1[(size_t)k * 384 + n];
        s1 += g2[k] * wv;
        s2 += lb2[k] * wv;
    }
    s1 = wave_sum(s1); s2 = wave_sum(s2);
    if (lane == 0) { c1[n] = s1; c2[n] = b1[n] + s2; }
}

// ---------------------------------------------------------------------------
// stats2: fold 8 column-partials per row -> (sa, ta) for the LN2+gate affine.
__global__ __launch_bounds__(256)
void stats2(const float* __restrict__ sums, float2* __restrict__ st2, int chunk_off)
{
    int r = chunk_off + blockIdx.x * 256 + threadIdx.x;
    float s = 0.f, ss = 0.f, d = 0.f;
#pragma unroll
    for (int p = 0; p < 8; ++p) {
        s  += sums[(size_t)(0 * 8 + p) * 65536 + r];
        ss += sums[(size_t)(1 * 8 + p) * 65536 + r];
        d  += sums[(size_t)(2 * 8 + p) * 65536 + r];
    }
    float gate = tanhf(d);
    float m = s * (1.f / 768.f), var = ss * (1.f / 768.f) - m * m;
    float den = rsqrtf(gate * gate * var + 1e-5f);
    st2[r] = make_float2(gate * den, -gate * m * den);
}

// ---------------------------------------------------------------------------
// Split-bf16 MFMA GEMM, packed-A.  2 blocks/CU, 256 thr / 4 waves (2x2),
// BM=128 BN=192, BK=32, single-phase k-loop.
// LDS buf (40KB): Ap@0 (16K, 128 rows x 128B packed) Bh@16K(12K) Bl@28K(12K).
// Units: 4x A (32 rows each) + 3x Bh + 3x Bl = 10 x 4KB.  VMW(10) schedule.
//   MODE 0: gelu epilogue -> packed u32 O + row-partial stats (sum,sq,dot qa).
//   MODE 1: affine epilogue h=gelu(sa*acc+ta*c1+c2), row-dot w2 -> partials.
#define VMW(N_) asm volatile("s_waitcnt vmcnt(" #N_ ")" ::: "memory")
#define SCB __builtin_amdgcn_sched_barrier(0)

#define STGA(U_, KT_) gl_lds16(spA[U_] + (KT_) * 32,                          \
    lds + (((KT_) & 1) ? BUFSZ : 0) + (U_) * 4096 + toff)
#define STGB(J_, KT_) gl_lds16(spB[J_] + (KT_) * 32,                          \
    lds + (((KT_) & 1) ? BUFSZ : 0) + 16384 + (J_) * 4096 + toff)

#define STGALL(KT_) do { STGA(0, KT_); STGA(1, KT_); STGA(2, KT_);            \
    STGA(3, KT_); STGB(0, KT_); STGB(1, KT_); STGB(2, KT_); STGB(3, KT_);     \
    STGB(4, KT_); STGB(5, KT_); } while (0)

#define RDAP do { _Pragma("unroll")                                           \
    for (int mf = 0; mf < 4; ++mf) {                                          \
        int rA = wm * 64 + mf * 16 + lr;                                      \
        const char* pr = bb + rA * 128;                                       \
        int x_ = rA & 7;                                                      \
        u32x4 p0 = *(const u32x4*)(pr + (((2 * lh) ^ x_) << 4));              \
        u32x4 p1 = *(const u32x4*)(pr + (((2 * lh + 1) ^ x_) << 4));          \
        unpack8(p0, p1, ah[mf], al[mf]);                                      \
    } } while (0)

#define RDB(dst, BOFF) do { _Pragma("unroll")                                 \
    for (int nf = 0; nf < 6; ++nf) {                                          \
        int rB = wn * 96 + nf * 16 + lr;                                      \
        dst[nf] = *(const short8v*)(bb + (BOFF) + rB * 64 +                   \
                                    ((lh ^ ((rB >> 1) & 3)) << 4));           \
    } } while (0)

#define BODY(KT_, NL_) do {                                                   \
    if (NL_) { STGALL((KT_) + 1); }                                           \
    SCB;                                                                      \
    if (NL_) { VMW(10); } else { VMW(0); }                                    \
    SCB;                                                                      \
    __builtin_amdgcn_s_barrier();            /* buf[KT_] staged for all */    \
    const char* bb = lds + (((KT_) & 1) ? BUFSZ : 0);                         \
    RDAP; RDB(bh, 16384); RDB(bl, 28672);                                     \
    asm volatile("s_waitcnt lgkmcnt(0)" ::: "memory");                        \
    SCB;                                                                      \
    __builtin_amdgcn_s_barrier();            /* reads done for all */         \
    __builtin_amdgcn_s_setprio(1);                                            \
    _Pragma("unroll")                                                         \
    for (int mf = 0; mf < 4; ++mf)                                            \
        _Pragma("unroll")                                                     \
        for (int nf = 0; nf < 6; ++nf) {                                      \
            acc[mf][nf] = __builtin_amdgcn_mfma_f32_16x16x32_bf16(            \
                ah[mf], bh[nf], acc[mf][nf], 0, 0, 0);                        \
            acc[mf][nf] = __builtin_amdgcn_mfma_f32_16x16x32_bf16(            \
                ah[mf], bl[nf], acc[mf][nf], 0, 0, 0);                        \
            acc[mf][nf] = __builtin_amdgcn_mfma_f32_16x16x32_bf16(            \
                al[mf], bh[nf], acc[mf][nf], 0, 0, 0);                        \
        }                                                                     \
    __builtin_amdgcn_s_setprio(0);                                            \
    SCB;                                                                      \
} while (0)

template<int MODE>
__global__ __launch_bounds__(256, 2)
void gemm8(const uint32_t* __restrict__ Ap_g,
           const short* __restrict__ Bh_g, const short* __restrict__ Bl_g,
           const float* __restrict__ bias, uint32_t* __restrict__ O_hl,
           const float* __restrict__ qa_p, float* __restrict__ sums,
           const float2* __restrict__ st2, const float* __restrict__ c1,
           const float* __restrict__ c2, const float* __restrict__ w2,
           float* __restrict__ partials, int chunk_off)
{
    constexpr int BUFSZ = 40960;              // 40 KB per buffer
    extern __shared__ __align__(16) char lds[];

    const int t = threadIdx.x;
    const int w = t >> 6, lane = t & 63;
    const int lr = lane & 15, lh = lane >> 4;
    const int wm = w >> 1, wn = w & 1;        // 2 x 2 wave grid

    const int gx = gridDim.x, nwg = gx * gridDim.y;
    int bidx = blockIdx.y * gx + blockIdx.x;
    int wid = (bidx & 7) * (nwg >> 3) + (bidx >> 3);
    const int bx = wid % gx, by = wid / gx;
    const int row0 = by * 128, col0 = bx * 192;

    // A stage pointers: unit u = rows u*32..u*32+32 of packed [row][768] u32.
    // thread t covers (local row t>>3, chunk t&7 of 8x16B); source chunk
    // pre-swizzled (t&7)^((t>>3)&7); LDS dest linear (u*4K + t*16).
    const int rA_ = t >> 3, cA_ = t & 7;
    const uint32_t* spA[4];
#pragma unroll
    for (int u = 0; u < 4; ++u)
        spA[u] = Ap_g + (size_t)(row0 + u * 32 + rA_) * KDIM
                      + ((cA_ ^ (rA_ & 7)) << 2);
    // B stage pointers: unit j covers 64 rows of bf16 [n][768]; 64B rows.
    const int rB_ = t >> 2, cB_ = t & 3;
    const int swzB = (cB_ ^ ((rB_ >> 1) & 3)) << 3;
    const short* spB[6];
    spB[0] = Bh_g + (size_t)(col0 + rB_)       * KDIM + swzB;
    spB[1] = Bh_g + (size_t)(col0 + 64 + rB_)  * KDIM + swzB;
    spB[2] = Bh_g + (size_t)(col0 + 128 + rB_) * KDIM + swzB;
    spB[3] = Bl_g + (size_t)(col0 + rB_)       * KDIM + swzB;
    spB[4] = Bl_g + (size_t)(col0 + 64 + rB_)  * KDIM + swzB;
    spB[5] = Bl_g + (size_t)(col0 + 128 + rB_) * KDIM + swzB;

    const int toff = t * 16;

    f32x4 acc[4][6] = {};
    short8v ah[4], al[4], bh[6], bl[6];

    STGALL(0);
    SCB;

    for (int kt = 0; kt < 24; kt += 2) {
        BODY(kt,     true);
        BODY(kt + 1, (kt + 1 < 23));
    }

    if (MODE == 0) {
        // cache qa_p slice for this block: 4 batch rows x 192 cols.
        __syncthreads();
        float* qal = (float*)lds;
        int bbase = (chunk_off >> 5) + (row0 >> 5);
        for (int j = t; j < 768; j += 256)
            qal[j] = qa_p[(size_t)(bbase + j / 192) * 768 + col0 + (j % 192)];
        __syncthreads();
#pragma unroll
        for (int mf = 0; mf < 4; ++mf) {
            const int bp = wm * 2 + (mf >> 1);
#pragma unroll
            for (int q = 0; q < 4; ++q) {
                int m = row0 + wm * 64 + mf * 16 + lh * 4 + q;
                float s = 0.f, ssq = 0.f, d = 0.f;
#pragma unroll
                for (int nf = 0; nf < 6; ++nf) {
                    int ncol = wn * 96 + nf * 16 + lr;
                    int n = col0 + ncol;
                    float gv = gelu_fast(acc[mf][nf][q] + bias[n]);
                    O_hl[(size_t)m * 768 + n] = packhl(gv);
                    s += gv; ssq += gv * gv; d += gv * qal[bp * 192 + ncol];
                }
                for (int o = 1; o < 16; o <<= 1) {
                    s += __shfl_xor(s, o); ssq += __shfl_xor(ssq, o); d += __shfl_xor(d, o);
                }
                if (lr == 0) {
                    int gr = chunk_off + m;
                    int pc = bx * 2 + wn;
                    sums[(size_t)(0 * 8 + pc) * 65536 + gr] = s;
                    sums[(size_t)(1 * 8 + pc) * 65536 + gr] = ssq;
                    sums[(size_t)(2 * 8 + pc) * 65536 + gr] = d;
                }
            }
        }
    } else {
        float c1v[6], c2v[6], wv[6];
#pragma unroll
        for (int nf = 0; nf < 6; ++nf) {
            int n = col0 + wn * 96 + nf * 16 + lr;
            c1v[nf] = c1[n]; c2v[nf] = c2[n]; wv[nf] = w2[n];
        }
        float rs[4][4] = {};
#pragma unroll
        for (int mf = 0; mf < 4; ++mf)
#pragma unroll
            for (int q = 0; q < 4; ++q) {
                int gm = chunk_off + row0 + wm * 64 + mf * 16 + lh * 4 + q;
                float2 st = st2[gm];
#pragma unroll
                for (int nf = 0; nf < 6; ++nf) {
                    float h = fmaf(st.x, acc[mf][nf][q], fmaf(st.y, c1v[nf], c2v[nf]));
                    rs[mf][q] += gelu_fast(h) * wv[nf];
                }
            }
#pragma unroll
        for (int mf = 0; mf < 4; ++mf)
#pragma unroll
            for (int q = 0; q < 4; ++q) {
                float vv = rs[mf][q];
                vv += __shfl_xor(vv, 1); vv += __shfl_xor(vv, 2);
                vv += __shfl_xor(vv, 4); vv += __shfl_xor(vv, 8);
                if (lr == 0) {
                    int gm = chunk_off + row0 + wm * 64 + mf * 16 + lh * 4 + q;
                    partials[(size_t)(bx * 2 + wn) * 65536 + gm] = vv;
                }
            }
    }
}

// ---------------------------------------------------------------------------
// f32 fallback GEMM for the small qa projection.
constexpr int BKF = 16;
__global__ __launch_bounds__(256)
void rowstats(const float* __restrict__ X, float2* __restrict__ st, int M)
{
    int wave = threadIdx.x >> 6, lane = threadIdx.x & 63;
    int row = blockIdx.x * 4 + wave;
    if (row >= M) return;
    const float4* xr = reinterpret_cast<const float4*>(X + (size_t)row * KDIM);
    float s = 0.f, ss = 0.f;
#pragma unroll
    for (int i = 0; i < 3; ++i) {
        float4 v = xr[lane + i * 64];
        s  += v.x + v.y + v.z + v.w;
        ss += v.x * v.x + v.y * v.y + v.z * v.z + v.w * v.w;
    }
    s = wave_sum(s); ss = wave_sum(ss);
    if (lane == 0) {
        float m = s * (1.0f / 768.0f);
        float var = ss * (1.0f / 768.0f) - m * m;
        float rstd = rsqrtf(var + 1e-5f);
        st[row] = make_float2(rstd, -m * rstd);
    }
}

template<int BM, int BN, int TM, int TN>
__global__ __launch_bounds__(256)
void gemm_fused(const float* __restrict__ X, const float2* __restrict__ st,
                const float* __restrict__ gw, const float* __restrict__ gb,
                const float* __restrict__ W, const float* __restrict__ bias,
                float* __restrict__ out, int M, int N)
{
    static_assert((BM / TM) * (BN / TN) == 256, "256 threads");
    __shared__ float As[BKF][BM];
    __shared__ float Bs[BKF][BN];
    const int t = threadIdx.x;
    constexpr int TXN = BN / TN;
    const int tx = t % TXN;
    const int ty = t / TXN;
    const int row0 = blockIdx.y * BM;
    const int col0 = blockIdx.x * BN;
    float acc[TM][TN] = {};
    constexpr int A_IT = BM * BKF / 4 / 256;
    constexpr int B_IT = BKF * BN / 4 / 256;
    for (int k0 = 0; k0 < KDIM; k0 += BKF) {
#pragma unroll
        for (int i = 0; i < A_IT; ++i) {
            int idx = t + i * 256;
            int r = idx >> 2;
            int c = (idx & 3) << 2;
            float4 xv = *reinterpret_cast<const float4*>(X + (size_t)(row0 + r) * KDIM + k0 + c);
            float2 s = st[row0 + r];
            float4 gv = *reinterpret_cast<const float4*>(gw + k0 + c);
            float4 bv = *reinterpret_cast<const float4*>(gb + k0 + c);
            As[c + 0][r] = fmaf(fmaf(xv.x, s.x, s.y), gv.x, bv.x);
            As[c + 1][r] = fmaf(fmaf(xv.y, s.x, s.y), gv.y, bv.y);
            As[c + 2][r] = fmaf(fmaf(xv.z, s.x, s.y), gv.z, bv.z);
            As[c + 3][r] = fmaf(fmaf(xv.w, s.x, s.y), gv.w, bv.w);
        }
#pragma unroll
        for (int i = 0; i < B_IT; ++i) {
            int idx = t + i * 256;
            int r = idx / (BN / 4);
            int c = (idx % (BN / 4)) << 2;
            *reinterpret_cast<float4*>(&Bs[r][c]) =
                *reinterpret_cast<const float4*>(W + (size_t)(k0 + r) * N + col0 + c);
        }
        __syncthreads();
#pragma unroll
        for (int kk = 0; kk < BKF; ++kk) {
            float a[TM], b[TN];
#pragma unroll
            for (int i = 0; i < TM; i += 4)
                *reinterpret_cast<float4*>(&a[i]) = *reinterpret_cast<const float4*>(&As[kk][ty * TM + i]);
#pragma unroll
            for (int j = 0; j < TN; j += 4)
                *reinterpret_cast<float4*>(&b[j]) = *reinterpret_cast<const float4*>(&Bs[kk][tx * TN + j]);
#pragma unroll
            for (int i = 0; i < TM; ++i)
#pragma unroll
                for (int j = 0; j < TN; ++j)
                    acc[i][j] = fmaf(a[i], b[j], acc[i][j]);
        }
        __syncthreads();
    }
#pragma unroll
    for (int i = 0; i < TM; ++i) {
        size_t row = row0 + ty * TM + i;
#pragma unroll
        for (int j = 0; j < TN; j += 4) {
            int col = col0 + tx * TN + j;
            float4 o;
            o.x = gelu_fast(acc[i][j + 0] + bias[col + 0]);
            o.y = gelu_fast(acc[i][j + 1] + bias[col + 1]);
            o.z = gelu_fast(acc[i][j + 2] + bias[col + 2]);
            o.w = gelu_fast(acc[i][j + 3] + bias[col + 3]);
            *reinterpret_cast<float4*>(out + row * N + col) = o;
        }
    }
}

// ---------------------------------------------------------------------------
// head: logits = sum(4 partials)+b2 -> softmax -> smooth -> softmax -> decode.
__global__ __launch_bounds__(64)
void head_kernel(const float* __restrict__ partials, const float* __restrict__ b2,
                 const float* __restrict__ sigma_p, float* __restrict__ out)
{
    int b = blockIdx.x, lane = threadIdx.x;
    __shared__ float ok[36];
    __shared__ float kg[32];
    __shared__ int sel[2];

    if (lane < 36) ok[lane] = 0.f;
    __syncthreads();

    float x = -3.4e38f;
    if (lane < 32) {
        int row = b * 32 + lane;
        x = b2[0];
#pragma unroll
        for (int p = 0; p < 4; ++p) x += partials[(size_t)p * 65536 + row];
    }
    float mx = wave_max(x);
    float e = (lane < 32) ? expf(x - mx) : 0.f;
    float sum = wave_sum(e);
    float ori = e / sum;
    if (lane < 32) {
        out[OFF_ORI + b * 32 + lane] = ori;
        ok[lane + 2] = ori;
    }
    __syncthreads();

    float sg = sigma_p[0];
    float kern[5]; float ks = 0.f;
#pragma unroll
    for (int k = 0; k < 5; ++k) { float xx = (float)(k - 2) / sg; kern[k] = expf(-0.5f * xx * xx); ks += kern[k]; }
    float sm = -3.4e38f;
    if (lane < 32) {
        sm = 0.f;
#pragma unroll
        for (int k = 0; k < 5; ++k) sm += (kern[k] / ks) * ok[lane + k];
    }
    float mx2 = wave_max(sm);
    float e2 = (lane < 32) ? expf(sm - mx2) : 0.f;
    float sum2 = wave_sum(e2);
    float kgv = e2 / sum2;
    if (lane < 32) {
        out[OFF_KG + b * 32 + lane] = kgv;
        kg[lane] = kgv;
    }
    __syncthreads();

    if (lane == 0) {
        int pm = 0; float bv = kg[0];
        for (int i = 1; i < 32; ++i) if (kg[i] > bv) { bv = kg[i]; pm = i; }
        float cum[33]; cum[0] = 0.f;
        for (int i = 0; i < 32; ++i) cum[i + 1] = cum[i] + kg[i];
        float bs = -3.4e38f; int bst = 0, ben = 0;
        const int wsz[3] = {1, 3, 5};
        for (int wi = 0; wi < 3; ++wi) {
            int w = wsz[wi];
            for (int s = 0; s + w <= 32; ++s) {
                if (pm >= s && pm < s + w) {
                    float sc = cum[s + w] - cum[s];
                    if (sc > bs) { bs = sc; bst = s; ben = s + w; }
                }
            }
        }
        out[OFF_MI + b * 2 + 0] = (float)bst;
        out[OFF_MI + b * 2 + 1] = (float)ben;
        out[OFF_ST + b] = (float)bst / 31.0f;
        out[OFF_ET + b] = (float)ben / 31.0f;
        sel[0] = bst; sel[1] = ben;
    }
    __syncthreads();
    if (lane < 32)
        out[OFF_MASK + b * 32 + lane] = (lane >= sel[0] && lane <= sel[1]) ? 1.0f : 0.0f;
}

// ---------------------------------------------------------------------------
extern "C" void kernel_launch(void* const* d_in, const int* in_sizes, int n_in,
                              void* d_out, int out_size, void* d_ws, size_t ws_size,
                              hipStream_t stream)
{
    const float* v      = (const float*)d_in[0];
    const float* qa     = (const float*)d_in[1];
    const float* vp_lng = (const float*)d_in[2];
    const float* vp_lnb = (const float*)d_in[3];
    const float* vp_w   = (const float*)d_in[4];
    const float* vp_b   = (const float*)d_in[5];
    const float* qp_lng = (const float*)d_in[6];
    const float* qp_lnb = (const float*)d_in[7];
    const float* qp_w   = (const float*)d_in[8];
    const float* qp_b   = (const float*)d_in[9];
    const float* g_lng  = (const float*)d_in[10];
    const float* g_lnb  = (const float*)d_in[11];
    const float* g_w1   = (const float*)d_in[12];
    const float* g_b1   = (const float*)d_in[13];
    const float* g_w2   = (const float*)d_in[14];
    const float* g_b2   = (const float*)d_in[15];
    const float* sigma  = (const float*)d_in[16];
    float* outf = (float*)d_out;

    // workspace layout (~220 MB)
    uint32_t* A1p = (uint32_t*)d_ws;                     // CHUNK*768 u32
    uint32_t* vp_hl = A1p + (size_t)CHUNK * KDIM;        // CHUNK*768 u32
    short* B1h = (short*)(vp_hl + (size_t)CHUNK * KDIM); // 768*768
    short* B1l = B1h + 768 * KDIM;
    short* B2h = B1l + 768 * KDIM;                       // 384*768
    short* B2l = B2h + 384 * KDIM;
    float* qa_p = (float*)(B2l + 384 * KDIM);            // 2048*768
    float* st_qa = qa_p + 2048 * KDIM;                   // 2048*2
    float* partials = st_qa + 4096;                      // 4*65536
    float* sums = partials + 4 * 65536;                  // 3*8*65536
    float2* st2 = (float2*)(sums + 24 * 65536);          // 65536
    float* c1 = (float*)(st2 + 65536);                   // 384
    float* c2 = c1 + 384;                                // 384

    // qa path (small, f32 vector GEMM)
    rowstats<<<512, 256, 0, stream>>>(qa, (float2*)st_qa, 2048);
    gemm_fused<64, 64, 4, 4><<<dim3(12, 32), 256, 0, stream>>>(
        qa, (const float2*)st_qa, qp_lng, qp_lnb, qp_w, qp_b, qa_p, 2048, 768);

    // weight prep: B1 = split(vp_w); B2 = split(g_lng (.) g_w1); colsums c1/c2
    prep_W<<<dim3(24, 24), 256, 0, stream>>>(vp_w, nullptr, B1h, B1l, 768);
    prep_W<<<dim3(12, 24), 256, 0, stream>>>(g_w1, g_lng, B2h, B2l, 384);
    colsums<<<96, 256, 0, stream>>>(g_w1, g_lng, g_lnb, g_b1, c1, c2);

    constexpr int LDS8 = 81920;   // 2 bufs x 40 KB -> 2 blocks/CU

    for (int c = 0; c < 65536; c += CHUNK) {
        prep_A1<<<CHUNK / 4, 256, 0, stream>>>(v + (size_t)c * KDIM, vp_lng, vp_lnb, A1p);
        // v_p = gelu(A1 @ vp_w^T + vp_b) -> packed vp_hl + row stats partials
        gemm8<0><<<dim3(4, CHUNK / 128), 256, LDS8, stream>>>(
            A1p, B1h, B1l, vp_b, vp_hl, qa_p, sums,
            nullptr, nullptr, nullptr, nullptr, nullptr, c);
        stats2<<<CHUNK / 256, 256, 0, stream>>>(sums, st2, c);
        // h = gelu(sa*(vp @ g2W1) + ta*c1 + c2); fused dot(g_w2) -> partials
        gemm8<1><<<dim3(2, CHUNK / 128), 256, LDS8, stream>>>(
            vp_hl, B2h, B2l, nullptr, nullptr, nullptr, nullptr,
            (const float2*)st2, c1, c2, g_w2, partials, c);
    }

    head_kernel<<<2048, 64, 0, stream>>>(partials, g_b2, sigma, outf);
}